// Round 5
// baseline (411.069 us; speedup 1.0000x reference)
//
#include <hip/hip_runtime.h>
#include <hip/hip_bf16.h>
#include <math.h>

#define SEQ 2048
#define NHEADS 32
#define NKVH 8
#define HD 128
#define HIDDEN 4096

typedef unsigned short u16;
typedef unsigned int u32;
typedef __attribute__((ext_vector_type(8))) __bf16 bf16x8;
typedef __attribute__((ext_vector_type(4))) float f32x4;
typedef __attribute__((ext_vector_type(16))) float f32x16;
typedef __attribute__((ext_vector_type(4))) u16 u16x4;
typedef __attribute__((ext_vector_type(4))) u32 u32x4;

__device__ __forceinline__ u16 f2bf(float f) {
  u32 u = __builtin_bit_cast(u32, f);
  u32 r = (u + 0x7fffu + ((u >> 16) & 1u)) >> 16;
  return (u16)r;
}
__device__ __forceinline__ float bf2f(u16 h) {
  return __builtin_bit_cast(float, ((u32)h) << 16);
}
__device__ __forceinline__ void gload_lds16(const void* g, void* l) {
  __builtin_amdgcn_global_load_lds(
      (const __attribute__((address_space(1))) u32*)g,
      (__attribute__((address_space(3))) u32*)l, 16, 0, 0);
}

#define BAR __builtin_amdgcn_s_barrier()
#define PRIO1 __builtin_amdgcn_s_setprio(1)
#define PRIO0 __builtin_amdgcn_s_setprio(0)
#define VMW(n) asm volatile("s_waitcnt vmcnt(" #n ")" ::: "memory")

// ---------------- fused prep: X f32->bf16 + Wq/Wk/Wv transpose f32->bf16^T ----------------
__global__ void __launch_bounds__(256) prep_all(
    const float* __restrict__ hs, u16* __restrict__ Xb,
    const float* __restrict__ Wq, u16* __restrict__ Wqt,
    const float* __restrict__ Wk, u16* __restrict__ Wkt,
    const float* __restrict__ Wv, u16* __restrict__ Wvt) {
  const int bid = blockIdx.x;
  if (bid < 8192) {  // X conversion, 4 f32/thread
    const int i = (bid * 256 + threadIdx.x) * 4;
    const float4 v = *(const float4*)(hs + i);
    u16x4 o;
    o.x = f2bf(v.x); o.y = f2bf(v.y); o.z = f2bf(v.z); o.w = f2bf(v.w);
    *(u16x4*)(Xb + i) = o;
    return;
  }
  __shared__ float tile[64][65];
  const float* src; u16* dst; int C, lc, tb;
  const int b2 = bid - 8192;
  if (b2 < 4096) { src = Wq; dst = Wqt; C = 4096; lc = 6; tb = b2; }
  else if (b2 < 5120) { src = Wk; dst = Wkt; C = 1024; lc = 4; tb = b2 - 4096; }
  else { src = Wv; dst = Wvt; C = 1024; lc = 4; tb = b2 - 5120; }
  const int r0 = (tb >> lc) * 64, c0 = (tb & ((1 << lc) - 1)) * 64;
  const int tx = threadIdx.x & 63, ty = threadIdx.x >> 6;
#pragma unroll
  for (int j = 0; j < 16; ++j)
    tile[ty + j * 4][tx] = src[(size_t)(r0 + ty + j * 4) * C + c0 + tx];
  __syncthreads();
#pragma unroll
  for (int j = 0; j < 16; ++j)
    dst[(size_t)(c0 + ty + j * 4) * 4096 + r0 + tx] = f2bf(tile[tx][ty + j * 4]);
}

// ---------------- RoPE in place on bf16 [SEQ][nheads*128], with output scale ----------------
__global__ void __launch_bounds__(256) rope_ip(u16* __restrict__ x, const int* __restrict__ pos,
                                               const int lognh, const float oscale) {
  const int idx = blockIdx.x * 256 + threadIdx.x;
  const int j = idx & 63;
  const int hh = (idx >> 6) & ((1 << lognh) - 1);
  const int s = idx >> (6 + lognh);
  if (s >= SEQ) return;
  const float p = (float)pos[s];
  const float invf = __expf((float)j * -0.14391156831212787f);  // -ln(10000)/64
  const float ang = p * invf;
  const float c = cosf(ang), sn = sinf(ang);
  u16* bp = x + ((size_t)s << (7 + lognh)) + hh * 128 + j;
  const float x1 = bf2f(bp[0]), x2 = bf2f(bp[64]);
  bp[0] = f2bf((x1 * c - x2 * sn) * oscale);
  bp[64] = f2bf((x2 * c + x1 * sn) * oscale);
}

// ---------------- transpose bf16 [R][C] -> bf16 [C][R] ----------------
__global__ void __launch_bounds__(256) trans_b2b(const u16* __restrict__ in,
                                                 u16* __restrict__ out, const int R, const int C) {
  __shared__ u16 tile[32][34];
  const int c0 = blockIdx.x * 32, r0 = blockIdx.y * 32;
  const int tx = threadIdx.x & 31, ty = threadIdx.x >> 5;
#pragma unroll
  for (int i = 0; i < 4; ++i)
    tile[ty + i * 8][tx] = in[(size_t)(r0 + ty + i * 8) * C + c0 + tx];
  __syncthreads();
#pragma unroll
  for (int i = 0; i < 4; ++i)
    out[(size_t)(c0 + ty + i * 8) * R + r0 + tx] = tile[tx][ty + i * 8];
}

// ================= 8-phase GEMM, 32x32x16 MFMA, BM=BN=256, BK=64, balanced reads =================
// 512 threads = 8 waves (2M x 4N); wave tile 128x64. Quadrants (MH,NH): (0,0),(0,1),(1,1),(1,0).
// A-frag sets: E (MH=0 halves), O (MH=1); B sets X/Y alternate. <=8 ds_read_b128 per phase.
// One half-region staged per phase; trailing vmcnt(6) drains the 3-phase-old stage.
template <int MH, int NH>
__device__ __forceinline__ void mfq32(f32x16 (&acc)[4][2], const bf16x8 (&afr)[2][4],
                                      const bf16x8 (&b)[4]) {
#pragma unroll
  for (int f = 0; f < 2; ++f)
#pragma unroll
    for (int ks = 0; ks < 4; ++ks)
      acc[MH * 2 + f][NH] = __builtin_amdgcn_mfma_f32_32x32x16_bf16(
          afr[f][ks], b[ks], acc[MH * 2 + f][NH], 0, 0, 0);
}

__global__ void __launch_bounds__(512, 2) gemm8p32(
    const u16* __restrict__ A, const u16* __restrict__ B0q, const u16* __restrict__ B1q,
    const u16* __restrict__ B2q, u16* __restrict__ C0, u16* __restrict__ C1,
    u16* __restrict__ C2, const float* __restrict__ Wsrc, u16* __restrict__ Wdst) {
  __shared__ u16 As[2][2][128 * 64];
  __shared__ u16 Bs[2][2][128 * 64];
  const int t = threadIdx.x;
  const int flat = blockIdx.x;
  const int swz = (flat & 7) * 32 + (flat >> 3);  // XCD swizzle over 256

  if (swz >= 192) {  // ---- folded Wo transpose (f32 [4096][4096] -> bf16^T) on XCDs 6,7 ----
    const int wid = swz - 192;  // rows [wid*64, +64)
    float* tf = (float*)&As[0][0][0];
    const int tx = t & 63, ty = t >> 6;
    const int r0 = wid * 64;
    for (int ct = 0; ct < 64; ++ct) {
      const int c0 = ct * 64;
#pragma unroll
      for (int i = 0; i < 8; ++i)
        tf[(ty + i * 8) * 65 + tx] = Wsrc[(size_t)(r0 + ty + i * 8) * 4096 + c0 + tx];
      __syncthreads();
#pragma unroll
      for (int i = 0; i < 8; ++i)
        Wdst[(size_t)(c0 + ty + i * 8) * 4096 + r0 + tx] = f2bf(tf[tx * 65 + ty + i * 8]);
      __syncthreads();
    }
    return;
  }

  const int lane = t & 63, w = t >> 6;
  const int wr = w >> 2, wc = w & 3;
  const int l31 = lane & 31, l5 = lane >> 5;

  int bxt = swz % 24;
  const int byt = swz / 24;
  const u16* Bp; u16* Cw; int Nn;
  if (bxt < 16) { Bp = B0q; Cw = C0; Nn = 4096; }
  else if (bxt < 20) { bxt -= 16; Bp = B1q; Cw = C1; Nn = 1024; }
  else { bxt -= 20; Bp = B2q; Cw = C2; Nn = 1024; }
  const int row0 = byt * 256, col0 = bxt * 256;

  auto stageA = [&](int buf, int half, int tile) {
#pragma unroll
    for (int g = 0; g < 2; ++g) {
      const int o = (g * 512 + t) * 16;
      const int ridx = o >> 7;
      const int slot = (o >> 4) & 7;
      const int gr = (ridx >> 6) * 128 + half * 64 + (ridx & 63);
      gload_lds16(A + (size_t)(row0 + gr) * 4096 + (tile << 6) + ((slot ^ (ridx & 7)) << 3),
                  (char*)&As[buf][half][0] + o);
    }
  };
  auto stageB = [&](int buf, int half, int tile) {
#pragma unroll
    for (int g = 0; g < 2; ++g) {
      const int o = (g * 512 + t) * 16;
      const int ridx = o >> 7;
      const int slot = (o >> 4) & 7;
      const int gn = (ridx >> 5) * 64 + half * 32 + (ridx & 31);
      gload_lds16(Bp + (size_t)(col0 + gn) * 4096 + (tile << 6) + ((slot ^ (ridx & 7)) << 3),
                  (char*)&Bs[buf][half][0] + o);
    }
  };

  bf16x8 aE[2][4], aO[2][4], bX[4], bY[4];
  // load one f-row (4 x ds_read_b128) of an A-half into dst
  auto loadAf = [&](int buf, int half, int f, bf16x8 (&dst)[4]) {
#pragma unroll
    for (int ks = 0; ks < 4; ++ks) {
      const int idx = wr * 64 + f * 32 + l31;
      const int slot = ks * 2 + l5;
      dst[ks] = *(const bf16x8*)((const char*)&As[buf][half][0] + idx * 128 +
                                 ((slot ^ (idx & 7)) << 4));
    }
  };
  auto loadB32 = [&](int buf, int half, bf16x8 (&dst)[4]) {
#pragma unroll
    for (int ks = 0; ks < 4; ++ks) {
      const int idx = wc * 32 + l31;
      const int slot = ks * 2 + l5;
      dst[ks] = *(const bf16x8*)((const char*)&Bs[buf][half][0] + idx * 128 +
                                 ((slot ^ (idx & 7)) << 4));
    }
  };

  f32x16 acc[4][2];
#pragma unroll
  for (int m_ = 0; m_ < 4; ++m_)
#pragma unroll
    for (int n_ = 0; n_ < 2; ++n_)
#pragma unroll
      for (int e = 0; e < 16; ++e) acc[m_][n_][e] = 0.f;

  const int nit = (4096 >> 6) >> 1;  // 32 pairs

  // prologue: stage tiles 0,1 fully (16 gloads); drain tile0 + A(1,0); preload E,X
  stageA(0, 0, 0); stageB(0, 0, 0); stageA(0, 1, 0); stageB(0, 1, 0);
  stageA(1, 0, 1); stageB(1, 0, 1); stageA(1, 1, 1); stageB(1, 1, 1);
  VMW(6);
  BAR;
  loadAf(0, 0, 0, aE[0]); loadAf(0, 0, 1, aE[1]); loadB32(0, 0, bX);
  BAR;

  for (int i = 0; i < nit - 1; ++i) {
    const int tb = 2 * i;
    // p0
    loadAf(0, 1, 0, aO[0]); loadB32(0, 1, bY);
    stageA(0, 0, tb + 2);
    BAR; PRIO1; mfq32<0, 0>(acc, aE, bX); PRIO0; VMW(6); BAR;
    // p1
    loadAf(0, 1, 1, aO[1]);
    stageB(0, 0, tb + 2);
    BAR; PRIO1; mfq32<0, 1>(acc, aE, bY); PRIO0; VMW(6); BAR;
    // p2
    loadAf(1, 0, 0, aE[0]);
    stageA(0, 1, tb + 2);
    BAR; PRIO1; mfq32<1, 1>(acc, aO, bY); PRIO0; VMW(6); BAR;
    // p3
    loadAf(1, 0, 1, aE[1]); loadB32(1, 0, bY);
    stageB(0, 1, tb + 2);
    BAR; PRIO1; mfq32<1, 0>(acc, aO, bX); PRIO0; VMW(6); BAR;
    // p4
    loadAf(1, 1, 0, aO[0]); loadB32(1, 1, bX);
    stageA(1, 0, tb + 3);
    BAR; PRIO1; mfq32<0, 0>(acc, aE, bY); PRIO0; VMW(6); BAR;
    // p5
    loadAf(1, 1, 1, aO[1]);
    stageB(1, 0, tb + 3);
    BAR; PRIO1; mfq32<0, 1>(acc, aE, bX); PRIO0; VMW(6); BAR;
    // p6
    loadAf(0, 0, 0, aE[0]);
    stageA(1, 1, tb + 3);
    BAR; PRIO1; mfq32<1, 1>(acc, aO, bX); PRIO0; VMW(6); BAR;
    // p7
    loadAf(0, 0, 1, aE[1]); loadB32(0, 0, bX);
    stageB(1, 1, tb + 3);
    BAR; PRIO1; mfq32<1, 0>(acc, aO, bY); PRIO0; VMW(6); BAR;
  }

  // peeled final pair: everything staged; drain all, no barriers needed between phases
  VMW(0);
  BAR;
  loadAf(0, 1, 0, aO[0]); loadAf(0, 1, 1, aO[1]); loadB32(0, 1, bY);
  PRIO1;
  mfq32<0, 0>(acc, aE, bX);
  mfq32<0, 1>(acc, aE, bY);
  PRIO0;
  loadAf(1, 0, 0, aE[0]); loadAf(1, 0, 1, aE[1]);
  PRIO1;
  mfq32<1, 1>(acc, aO, bY);
  mfq32<1, 0>(acc, aO, bX);
  PRIO0;
  loadB32(1, 0, bY); loadB32(1, 1, bX);
  loadAf(1, 1, 0, aO[0]); loadAf(1, 1, 1, aO[1]);
  PRIO1;
  mfq32<0, 0>(acc, aE, bY);
  mfq32<0, 1>(acc, aE, bX);
  mfq32<1, 1>(acc, aO, bX);
  mfq32<1, 0>(acc, aO, bY);
  PRIO0;

  // epilogue: 32x32 D layout col=l&31, row=(reg&3)+8*(reg>>2)+4*(l>>5)
#pragma unroll
  for (int am = 0; am < 4; ++am)
#pragma unroll
    for (int an = 0; an < 2; ++an) {
      const int colb = col0 + wc * 64 + an * 32 + l31;
#pragma unroll
      for (int q = 0; q < 4; ++q) {
        const int rowb = row0 + wr * 128 + am * 32 + q * 8 + l5 * 4;
#pragma unroll
        for (int rr = 0; rr < 4; ++rr)
          Cw[(size_t)(rowb + rr) * Nn + colb] = f2bf(acc[am][an][q * 4 + rr]);
      }
    }
}

// ================= 8-phase GEMM, 16x16x32 MFMA, BM=128, BN=256 (Wo, f32 out), balanced =================
template <int MH, int NH>
__device__ __forceinline__ void mfq16(f32x4 (&acc)[4][4], const bf16x8 (&af)[2][2],
                                      const bf16x8 (&b)[2][2]) {
#pragma unroll
  for (int f = 0; f < 2; ++f)
#pragma unroll
    for (int e = 0; e < 2; ++e)
#pragma unroll
      for (int ks = 0; ks < 2; ++ks)
        acc[MH * 2 + f][NH * 2 + e] = __builtin_amdgcn_mfma_f32_16x16x32_bf16(
            af[f][ks], b[e][ks], acc[MH * 2 + f][NH * 2 + e], 0, 0, 0);
}

__global__ void __launch_bounds__(512, 2) gemm8p16(
    const u16* __restrict__ A, const u16* __restrict__ B, float* __restrict__ C) {
  __shared__ u16 As[2][2][64 * 64];
  __shared__ u16 Bs[2][2][128 * 64];
  const int t = threadIdx.x;
  const int lane = t & 63, w = t >> 6;
  const int wr = w >> 2, wc = w & 3;
  const int l15 = lane & 15, l4 = lane >> 4;

  const int flat = blockIdx.x;
  const int swz = (flat & 7) * 32 + (flat >> 3);
  const int bxt = swz & 15, byt = swz >> 4;
  const int row0 = byt * 128, col0 = bxt * 256;

  auto stageA = [&](int buf, int half, int tile) {
    const int o = t * 16;
    const int ridx = o >> 7;
    const int slot = (o >> 4) & 7;
    const int gr = (ridx >> 5) * 64 + half * 32 + (ridx & 31);
    gload_lds16(A + (size_t)(row0 + gr) * 4096 + (tile << 6) + ((slot ^ (ridx & 7)) << 3),
                (char*)&As[buf][half][0] + o);
  };
  auto stageB = [&](int buf, int half, int tile) {
#pragma unroll
    for (int g = 0; g < 2; ++g) {
      const int o = (g * 512 + t) * 16;
      const int ridx = o >> 7;
      const int slot = (o >> 4) & 7;
      const int gn = (ridx >> 5) * 64 + half * 32 + (ridx & 31);
      gload_lds16(B + (size_t)(col0 + gn) * 4096 + (tile << 6) + ((slot ^ (ridx & 7)) << 3),
                  (char*)&Bs[buf][half][0] + o);
    }
  };

  bf16x8 aE[2][2], aO[2][2], bX[2][2], bY[2][2];
  auto loadAf = [&](int buf, int half, int f, bf16x8 (&dst)[2]) {
#pragma unroll
    for (int ks = 0; ks < 2; ++ks) {
      const int idx = wr * 32 + f * 16 + l15;
      const int slot = ks * 4 + l4;
      dst[ks] = *(const bf16x8*)((const char*)&As[buf][half][0] + idx * 128 +
                                 ((slot ^ (idx & 7)) << 4));
    }
  };
  auto loadB16 = [&](int buf, int half, bf16x8 (&dst)[2][2]) {
#pragma unroll
    for (int e = 0; e < 2; ++e)
#pragma unroll
      for (int ks = 0; ks < 2; ++ks) {
        const int idx = wc * 32 + e * 16 + l15;
        const int slot = ks * 4 + l4;
        dst[e][ks] = *(const bf16x8*)((const char*)&Bs[buf][half][0] + idx * 128 +
                                      ((slot ^ (idx & 7)) << 4));
      }
  };

  f32x4 acc[4][4];
#pragma unroll
  for (int m_ = 0; m_ < 4; ++m_)
#pragma unroll
    for (int n_ = 0; n_ < 4; ++n_) acc[m_][n_] = f32x4{0.f, 0.f, 0.f, 0.f};

  const int nit = (4096 >> 6) >> 1;

  stageA(0, 0, 0); stageB(0, 0, 0); stageA(0, 1, 0); stageB(0, 1, 0);
  stageA(1, 0, 1); stageB(1, 0, 1); stageA(1, 1, 1); stageB(1, 1, 1);
  VMW(5);
  BAR;
  loadAf(0, 0, 0, aE[0]); loadAf(0, 0, 1, aE[1]); loadB16(0, 0, bX);
  BAR;

  for (int i = 0; i < nit - 1; ++i) {
    const int tb = 2 * i;
    // p0
    loadAf(0, 1, 0, aO[0]); loadB16(0, 1, bY);
    stageA(0, 0, tb + 2);
    BAR; PRIO1; mfq16<0, 0>(acc, aE, bX); PRIO0; VMW(4); BAR;
    // p1
    loadAf(0, 1, 1, aO[1]);
    stageB(0, 0, tb + 2);
    BAR; PRIO1; mfq16<0, 1>(acc, aE, bY); PRIO0; VMW(4); BAR;
    // p2
    loadAf(1, 0, 0, aE[0]);
    stageA(0, 1, tb + 2);
    BAR; PRIO1; mfq16<1, 1>(acc, aO, bY); PRIO0; VMW(4); BAR;
    // p3
    loadAf(1, 0, 1, aE[1]); loadB16(1, 0, bY);
    stageB(0, 1, tb + 2);
    BAR; PRIO1; mfq16<1, 0>(acc, aO, bX); PRIO0; VMW(4); BAR;
    // p4
    loadAf(1, 1, 0, aO[0]); loadB16(1, 1, bX);
    stageA(1, 0, tb + 3);
    BAR; PRIO1; mfq16<0, 0>(acc, aE, bY); PRIO0; VMW(4); BAR;
    // p5
    loadAf(1, 1, 1, aO[1]);
    stageB(1, 0, tb + 3);
    BAR; PRIO1; mfq16<0, 1>(acc, aE, bX); PRIO0; VMW(4); BAR;
    // p6
    loadAf(0, 0, 0, aE[0]);
    stageA(1, 1, tb + 3);
    BAR; PRIO1; mfq16<1, 1>(acc, aO, bX); PRIO0; VMW(4); BAR;
    // p7
    loadAf(0, 0, 1, aE[1]); loadB16(0, 0, bX);
    stageB(1, 1, tb + 3);
    BAR; PRIO1; mfq16<1, 0>(acc, aO, bY); PRIO0; VMW(4); BAR;
  }

  VMW(0);
  BAR;
  loadAf(0, 1, 0, aO[0]); loadAf(0, 1, 1, aO[1]); loadB16(0, 1, bY);
  PRIO1;
  mfq16<0, 0>(acc, aE, bX);
  mfq16<0, 1>(acc, aE, bY);
  PRIO0;
  loadAf(1, 0, 0, aE[0]); loadAf(1, 0, 1, aE[1]);
  PRIO1;
  mfq16<1, 1>(acc, aO, bY);
  mfq16<1, 0>(acc, aO, bX);
  PRIO0;
  loadB16(1, 0, bY); loadB16(1, 1, bX);
  loadAf(1, 1, 0, aO[0]); loadAf(1, 1, 1, aO[1]);
  PRIO1;
  mfq16<0, 0>(acc, aE, bY);
  mfq16<0, 1>(acc, aE, bX);
  mfq16<1, 1>(acc, aO, bX);
  mfq16<1, 0>(acc, aO, bY);
  PRIO0;

#pragma unroll
  for (int am = 0; am < 4; ++am) {
    const int rowb = row0 + wr * 64 + (am >> 1) * 32 + (am & 1) * 16 + l4 * 4;
#pragma unroll
    for (int an = 0; an < 4; ++an) {
      const int colb = col0 + wc * 64 + (an >> 1) * 32 + (an & 1) * 16 + l15;
#pragma unroll
      for (int r = 0; r < 4; ++r)
        C[(size_t)(rowb + r) * 4096 + colb] = acc[am][an][r];
    }
  }
}

// ---------------- attention staging: K tile [64][128] + V^T tile [128][64], swizzled ----------------
__device__ __forceinline__ void stage_kv(const u16* __restrict__ k, const u16* __restrict__ vt,
                                         const int kvh, const int kv0, u16* KsB, u16* VsB,
                                         const int t) {
#pragma unroll
  for (int i = 0; i < 4; ++i) {
    const int o = (i * 256 + t) * 16;
    const int row = o >> 8;
    const int slot = (o >> 4) & 15;
    gload_lds16(k + (size_t)(kv0 + row) * (NKVH * HD) + kvh * HD + ((slot ^ (row & 7)) << 3),
                (char*)KsB + o);
  }
#pragma unroll
  for (int i = 0; i < 4; ++i) {
    const int o = (i * 256 + t) * 16;
    const int row = o >> 7;
    const int slot = (o >> 4) & 7;
    gload_lds16(vt + (size_t)(kvh * HD + row) * SEQ + kv0 + ((slot ^ (row & 7)) << 3),
                (char*)VsB + o);
  }
}

// ---------------- causal GQA flash attention, swapped-QK in-register softmax ----------------
__global__ void __launch_bounds__(256) attn_fwd(const u16* __restrict__ q, const u16* __restrict__ k,
                                                const u16* __restrict__ vt, u16* __restrict__ ctx) {
  __shared__ u16 Ks[2][64 * 128];
  __shared__ u16 Vs[2][128 * 64];
  const int t = threadIdx.x, lane = t & 63, w = t >> 6;
  const int h = blockIdx.x;
  const int qb = (int)gridDim.y - 1 - (int)blockIdx.y;
  const int kvh = h >> 2;
  const int q0 = qb * 64;
  const int sq_base = q0 + w * 16;
  const int l15 = lane & 15, l4 = lane >> 4;
  const int sq_abs = sq_base + l15;

  bf16x8 qf[4];
  {
    const u16* qp = q + (size_t)sq_abs * (NHEADS * HD) + h * HD + l4 * 8;
#pragma unroll
    for (int kb = 0; kb < 4; ++kb) qf[kb] = *(const bf16x8*)(qp + kb * 32);
  }
  f32x4 po[8];
#pragma unroll
  for (int i = 0; i < 8; ++i) po[i] = f32x4{0.f, 0.f, 0.f, 0.f};
  float mrow = -1e30f;
  float lrow = 0.f;

  const int nb = qb + 1;
  stage_kv(k, vt, kvh, 0, Ks[0], Vs[0], t);
  __syncthreads();
  int cur = 0;

  for (int b = 0; b < nb; ++b) {
    if (b + 1 < nb) stage_kv(k, vt, kvh, (b + 1) * 64, Ks[cur ^ 1], Vs[cur ^ 1], t);

    f32x4 st[4];
#pragma unroll
    for (int c = 0; c < 4; ++c) st[c] = f32x4{0.f, 0.f, 0.f, 0.f};
#pragma unroll
    for (int c = 0; c < 4; ++c) {
      const int row = c * 16 + l15;
#pragma unroll
      for (int kb = 0; kb < 4; ++kb) {
        const int slot = kb * 4 + l4;
        bf16x8 bk = *(const bf16x8*)((const char*)Ks[cur] + row * 256 + ((slot ^ (row & 7)) << 4));
        st[c] = __builtin_amdgcn_mfma_f32_16x16x32_bf16(bk, qf[kb], st[c], 0, 0, 0);
      }
    }

    if (b == nb - 1) {
#pragma unroll
      for (int c = 0; c < 4; ++c)
#pragma unroll
        for (int r = 0; r < 4; ++r) {
          const int sk = b * 64 + c * 16 + l4 * 4 + r;
          if (sk > sq_abs) st[c][r] = -1e30f;
        }
    }

    float rmax = -3e38f;
#pragma unroll
    for (int c = 0; c < 4; ++c)
      rmax = fmaxf(rmax, fmaxf(fmaxf(st[c][0], st[c][1]), fmaxf(st[c][2], st[c][3])));
    rmax = fmaxf(rmax, __shfl_xor(rmax, 16, 64));
    rmax = fmaxf(rmax, __shfl_xor(rmax, 32, 64));

    const bool skip = __all(rmax <= mrow + 8.f);
    const float mnew = skip ? mrow : fmaxf(mrow, rmax);

    float rs = 0.f;
#pragma unroll
    for (int c = 0; c < 4; ++c) {
      const float e0 = exp2f(st[c][0] - mnew), e1 = exp2f(st[c][1] - mnew);
      const float e2 = exp2f(st[c][2] - mnew), e3 = exp2f(st[c][3] - mnew);
      st[c][0] = e0; st[c][1] = e1; st[c][2] = e2; st[c][3] = e3;
      rs += (e0 + e1) + (e2 + e3);
    }
    rs += __shfl_xor(rs, 16, 64);
    rs += __shfl_xor(rs, 32, 64);

    if (!skip) {
      const float alpha = exp2f(mrow - mnew);
      mrow = mnew;
      lrow = lrow * alpha + rs;
      float av[4];
#pragma unroll
      for (int r = 0; r < 4; ++r) av[r] = __shfl(alpha, l4 * 4 + r, 16);
#pragma unroll
      for (int db = 0; db < 8; ++db)
#pragma unroll
        for (int r = 0; r < 4; ++r) po[db][r] *= av[r];
    } else {
      lrow += rs;
    }

    u32 pk[4][2];
#pragma unroll
    for (int c = 0; c < 4; ++c) {
      pk[c][0] = (u32)f2bf(st[c][0]) | ((u32)f2bf(st[c][1]) << 16);
      pk[c][1] = (u32)f2bf(st[c][2]) | ((u32)f2bf(st[c][3]) << 16);
    }
    const int src01 = l15 + ((lane & 16) << 1);
    const int src23 = src01 + 16;
    const bool lo = (lane & 32) == 0;
#pragma unroll
    for (int kb2 = 0; kb2 < 2; ++kb2) {
      const int c0 = kb2 * 2, c1 = c0 + 1;
      const u32 a0 = (u32)__shfl((int)pk[c0][0], src01, 64);
      const u32 a1 = (u32)__shfl((int)pk[c0][1], src01, 64);
      const u32 a2 = (u32)__shfl((int)pk[c0][0], src23, 64);
      const u32 a3 = (u32)__shfl((int)pk[c0][1], src23, 64);
      const u32 b0 = (u32)__shfl((int)pk[c1][0], src01, 64);
      const u32 b1 = (u32)__shfl((int)pk[c1][1], src01, 64);
      const u32 b2 = (u32)__shfl((int)pk[c1][0], src23, 64);
      const u32 b3 = (u32)__shfl((int)pk[c1][1], src23, 64);
      u32x4 wq;
      wq.x = lo ? a0 : b0;
      wq.y = lo ? a1 : b1;
      wq.z = lo ? a2 : b2;
      wq.w = lo ? a3 : b3;
      const bf16x8 pa = __builtin_bit_cast(bf16x8, wq);
#pragma unroll
      for (int db = 0; db < 8; ++db) {
        const int vrow = db * 16 + l15;
        const int pslot = kb2 * 4 + l4;
        bf16x8 bv = *(const bf16x8*)((const char*)Vs[cur] + vrow * 128 + ((pslot ^ (vrow & 7)) << 4));
        po[db] = __builtin_amdgcn_mfma_f32_16x16x32_bf16(pa, bv, po[db], 0, 0, 0);
      }
    }
    __syncthreads();
    cur ^= 1;
  }

  float rl[4];
#pragma unroll
  for (int r = 0; r < 4; ++r) rl[r] = 1.f / __shfl(lrow, l4 * 4 + r, 16);
#pragma unroll
  for (int db = 0; db < 8; ++db)
#pragma unroll
    for (int r = 0; r < 4; ++r) {
      const int sq = sq_base + l4 * 4 + r;
      const int d = db * 16 + l15;
      ctx[(size_t)sq * (NHEADS * HD) + h * HD + d] = f2bf(po[db][r] * rl[r]);
    }
}

extern "C" void kernel_launch(void* const* d_in, const int* in_sizes, int n_in,
                              void* d_out, int out_size, void* d_ws, size_t ws_size,
                              hipStream_t stream) {
  const float* hs = (const float*)d_in[0];
  const int* pos = (const int*)d_in[1];
  const float* Wq = (const float*)d_in[2];
  const float* Wk = (const float*)d_in[3];
  const float* Wv = (const float*)d_in[4];
  const float* Wo = (const float*)d_in[5];

  u16* ws = (u16*)d_ws;
  u16* Xb = ws;                                   // [2048][4096]
  u16* Wqt = Xb + (size_t)2048 * 4096;            // [4096][4096]
  u16* Wkt = Wqt + (size_t)4096 * 4096;           // [1024][4096]
  u16* Wvt = Wkt + (size_t)1024 * 4096;           // [1024][4096]
  u16* Wot = Wvt + (size_t)1024 * 4096;           // [4096][4096]
  u16* qb = Wot + (size_t)4096 * 4096;            // [2048][4096]
  u16* kb = qb + (size_t)2048 * 4096;             // [2048][1024]
  u16* vb = kb + (size_t)2048 * 1024;             // [2048][1024]
  u16* vtb = vb + (size_t)2048 * 1024;            // [1024][2048]
  u16* ctx = vtb + (size_t)1024 * 2048;           // [2048][4096]
  const size_t need = ((size_t)(ctx - ws) + (size_t)2048 * 4096) * 2;
  if (ws_size < need) return;

  // fused X conversion + Wq/Wk/Wv transposes
  prep_all<<<14336, 256, 0, stream>>>(hs, Xb, Wq, Wqt, Wk, Wkt, Wv, Wvt);

  // fused Q+K+V projections (192 gemm blocks) + folded Wo transpose (64 blocks)
  gemm8p32<<<256, 512, 0, stream>>>(Xb, Wqt, Wkt, Wvt, qb, kb, vb, Wo, Wot);

  const float qscale = 0.08838834764831845f * 1.44269504088896340f;  // 1/sqrt(128)*log2(e)
  rope_ip<<<16384, 256, 0, stream>>>(qb, pos, 5, qscale);
  rope_ip<<<4096, 256, 0, stream>>>(kb, pos, 3, 1.0f);

  trans_b2b<<<dim3(32, 64), 256, 0, stream>>>(vb, vtb, 2048, 1024);

  attn_fwd<<<dim3(32, 32), 256, 0, stream>>>(qb, kb, vtb, ctx);

  // output projection -> fp32 d_out
  gemm8p16<<<256, 512, 0, stream>>>(ctx, Wot, (float*)d_out);
}

// Round 6
// 346.359 us; speedup vs baseline: 1.1868x; 1.1868x over previous
//
#include <hip/hip_runtime.h>
#include <hip/hip_bf16.h>
#include <math.h>

#define SEQ 2048
#define NHEADS 32
#define NKVH 8
#define HD 128
#define HIDDEN 4096

typedef unsigned short u16;
typedef unsigned int u32;
typedef __attribute__((ext_vector_type(8))) __bf16 bf16x8;
typedef __attribute__((ext_vector_type(4))) float f32x4;
typedef __attribute__((ext_vector_type(16))) float f32x16;
typedef __attribute__((ext_vector_type(4))) u16 u16x4;
typedef __attribute__((ext_vector_type(4))) u32 u32x4;

__device__ __forceinline__ u16 f2bf(float f) {
  u32 u = __builtin_bit_cast(u32, f);
  u32 r = (u + 0x7fffu + ((u >> 16) & 1u)) >> 16;
  return (u16)r;
}
__device__ __forceinline__ float bf2f(u16 h) {
  return __builtin_bit_cast(float, ((u32)h) << 16);
}
__device__ __forceinline__ void gload_lds16(const void* g, void* l) {
  __builtin_amdgcn_global_load_lds(
      (const __attribute__((address_space(1))) u32*)g,
      (__attribute__((address_space(3))) u32*)l, 16, 0, 0);
}

#define BAR __builtin_amdgcn_s_barrier()
#define PRIO1 __builtin_amdgcn_s_setprio(1)
#define PRIO0 __builtin_amdgcn_s_setprio(0)
#define VMW(n) asm volatile("s_waitcnt vmcnt(" #n ")" ::: "memory")

// ---------------- fused prep: X f32->bf16 + Wq/Wk/Wv transpose f32->bf16^T ----------------
__global__ void __launch_bounds__(256) prep_all(
    const float* __restrict__ hs, u16* __restrict__ Xb,
    const float* __restrict__ Wq, u16* __restrict__ Wqt,
    const float* __restrict__ Wk, u16* __restrict__ Wkt,
    const float* __restrict__ Wv, u16* __restrict__ Wvt) {
  const int bid = blockIdx.x;
  if (bid < 8192) {  // X conversion, 4 f32/thread
    const int i = (bid * 256 + threadIdx.x) * 4;
    const float4 v = *(const float4*)(hs + i);
    u16x4 o;
    o.x = f2bf(v.x); o.y = f2bf(v.y); o.z = f2bf(v.z); o.w = f2bf(v.w);
    *(u16x4*)(Xb + i) = o;
    return;
  }
  __shared__ float tile[64][65];
  const float* src; u16* dst; int C, lc, tb;
  const int b2 = bid - 8192;
  if (b2 < 4096) { src = Wq; dst = Wqt; C = 4096; lc = 6; tb = b2; }
  else if (b2 < 5120) { src = Wk; dst = Wkt; C = 1024; lc = 4; tb = b2 - 4096; }
  else { src = Wv; dst = Wvt; C = 1024; lc = 4; tb = b2 - 5120; }
  const int r0 = (tb >> lc) * 64, c0 = (tb & ((1 << lc) - 1)) * 64;
  const int tx = threadIdx.x & 63, ty = threadIdx.x >> 6;
#pragma unroll
  for (int j = 0; j < 16; ++j)
    tile[ty + j * 4][tx] = src[(size_t)(r0 + ty + j * 4) * C + c0 + tx];
  __syncthreads();
#pragma unroll
  for (int j = 0; j < 16; ++j)
    dst[(size_t)(c0 + ty + j * 4) * 4096 + r0 + tx] = f2bf(tile[tx][ty + j * 4]);
}

// ---------------- fused post-QKV: RoPE(q)+RoPE(k) + V transpose ----------------
__global__ void __launch_bounds__(256) post_qkv(u16* __restrict__ qb, u16* __restrict__ kb,
                                                const u16* __restrict__ vb, u16* __restrict__ vtb,
                                                const int* __restrict__ pos) {
  const int bid = blockIdx.x;
  if (bid < 20480) {  // RoPE
    u16* x; int lognh; float oscale;
    int idx;
    if (bid < 16384) {
      x = qb; lognh = 5;
      oscale = 0.08838834764831845f * 1.44269504088896340f;  // 1/sqrt(128)*log2(e)
      idx = bid * 256 + threadIdx.x;
    } else {
      x = kb; lognh = 3; oscale = 1.0f;
      idx = (bid - 16384) * 256 + threadIdx.x;
    }
    const int j = idx & 63;
    const int hh = (idx >> 6) & ((1 << lognh) - 1);
    const int s = idx >> (6 + lognh);
    if (s >= SEQ) return;
    const float p = (float)pos[s];
    const float invf = __expf((float)j * -0.14391156831212787f);  // -ln(10000)/64
    const float ang = p * invf;
    const float c = cosf(ang), sn = sinf(ang);
    u16* bp = x + ((size_t)s << (7 + lognh)) + hh * 128 + j;
    const float x1 = bf2f(bp[0]), x2 = bf2f(bp[64]);
    bp[0] = f2bf((x1 * c - x2 * sn) * oscale);
    bp[64] = f2bf((x2 * c + x1 * sn) * oscale);
    return;
  }
  // V transpose: vb [2048][1024] -> vtb [1024][2048]
  __shared__ u16 tile[32][34];
  const int b2 = bid - 20480;
  const int c0 = (b2 & 31) * 32, r0 = (b2 >> 5) * 32;
  const int tx = threadIdx.x & 31, ty = threadIdx.x >> 5;
#pragma unroll
  for (int i = 0; i < 4; ++i)
    tile[ty + i * 8][tx] = vb[(size_t)(r0 + ty + i * 8) * 1024 + c0 + tx];
  __syncthreads();
#pragma unroll
  for (int i = 0; i < 4; ++i)
    vtb[(size_t)(c0 + ty + i * 8) * 2048 + r0 + tx] = tile[tx][ty + i * 8];
}

// ================= 8-phase GEMM, 32x32x16 MFMA, BM=BN=256, BK=64 =================
// Earliest-legal stage rotation: each half staged the phase after its last read.
// Stage->read distance 6-7 phases; vmcnt(8) at p3/p7 only forces >=4-phase-old loads.
template <int MH, int NH>
__device__ __forceinline__ void mfq32(f32x16 (&acc)[4][2], const bf16x8 (&afr)[2][4],
                                      const bf16x8 (&b)[4]) {
#pragma unroll
  for (int f = 0; f < 2; ++f)
#pragma unroll
    for (int ks = 0; ks < 4; ++ks)
      acc[MH * 2 + f][NH] = __builtin_amdgcn_mfma_f32_32x32x16_bf16(
          afr[f][ks], b[ks], acc[MH * 2 + f][NH], 0, 0, 0);
}

__global__ void __launch_bounds__(512, 2) gemm8p32(
    const u16* __restrict__ A, const u16* __restrict__ B0q, const u16* __restrict__ B1q,
    const u16* __restrict__ B2q, u16* __restrict__ C0, u16* __restrict__ C1,
    u16* __restrict__ C2, const float* __restrict__ Wsrc, u16* __restrict__ Wdst) {
  __shared__ u16 As[2][2][128 * 64];
  __shared__ u16 Bs[2][2][128 * 64];
  const int t = threadIdx.x;
  const int flat = blockIdx.x;
  const int swz = (flat & 7) * 32 + (flat >> 3);  // XCD swizzle over 256

  if (swz >= 192) {  // ---- folded Wo transpose (f32 [4096][4096] -> bf16^T) on XCDs 6,7 ----
    const int wid = swz - 192;  // rows [wid*64, +64)
    float* tf = (float*)&As[0][0][0];
    const int tx = t & 63, ty = t >> 6;
    const int r0 = wid * 64;
    for (int ct = 0; ct < 64; ++ct) {
      const int c0 = ct * 64;
#pragma unroll
      for (int i = 0; i < 8; ++i)
        tf[(ty + i * 8) * 65 + tx] = Wsrc[(size_t)(r0 + ty + i * 8) * 4096 + c0 + tx];
      __syncthreads();
#pragma unroll
      for (int i = 0; i < 8; ++i)
        Wdst[(size_t)(c0 + ty + i * 8) * 4096 + r0 + tx] = f2bf(tf[tx * 65 + ty + i * 8]);
      __syncthreads();
    }
    return;
  }

  const int lane = t & 63, w = t >> 6;
  const int wr = w >> 2, wc = w & 3;
  const int l31 = lane & 31, l5 = lane >> 5;

  int bxt = swz % 24;
  const int byt = swz / 24;
  const u16* Bp; u16* Cw; int Nn;
  if (bxt < 16) { Bp = B0q; Cw = C0; Nn = 4096; }
  else if (bxt < 20) { bxt -= 16; Bp = B1q; Cw = C1; Nn = 1024; }
  else { bxt -= 20; Bp = B2q; Cw = C2; Nn = 1024; }
  const int row0 = byt * 256, col0 = bxt * 256;

  auto stageA = [&](int buf, int half, int tile) {
#pragma unroll
    for (int g = 0; g < 2; ++g) {
      const int o = (g * 512 + t) * 16;
      const int ridx = o >> 7;
      const int slot = (o >> 4) & 7;
      const int gr = (ridx >> 6) * 128 + half * 64 + (ridx & 63);
      gload_lds16(A + (size_t)(row0 + gr) * 4096 + (tile << 6) + ((slot ^ (ridx & 7)) << 3),
                  (char*)&As[buf][half][0] + o);
    }
  };
  auto stageB = [&](int buf, int half, int tile) {
#pragma unroll
    for (int g = 0; g < 2; ++g) {
      const int o = (g * 512 + t) * 16;
      const int ridx = o >> 7;
      const int slot = (o >> 4) & 7;
      const int gn = (ridx >> 5) * 64 + half * 32 + (ridx & 31);
      gload_lds16(Bp + (size_t)(col0 + gn) * 4096 + (tile << 6) + ((slot ^ (ridx & 7)) << 3),
                  (char*)&Bs[buf][half][0] + o);
    }
  };

  bf16x8 afr[2][4], bf0[4], bf1[4];
  auto loadA32 = [&](int buf, int half) {
#pragma unroll
    for (int f = 0; f < 2; ++f)
#pragma unroll
      for (int ks = 0; ks < 4; ++ks) {
        const int idx = wr * 64 + f * 32 + l31;
        const int slot = ks * 2 + l5;
        afr[f][ks] = *(const bf16x8*)((const char*)&As[buf][half][0] + idx * 128 +
                                      ((slot ^ (idx & 7)) << 4));
      }
  };
  auto loadB32 = [&](int buf, int half, bf16x8 (&dst)[4]) {
#pragma unroll
    for (int ks = 0; ks < 4; ++ks) {
      const int idx = wc * 32 + l31;
      const int slot = ks * 2 + l5;
      dst[ks] = *(const bf16x8*)((const char*)&Bs[buf][half][0] + idx * 128 +
                                 ((slot ^ (idx & 7)) << 4));
    }
  };

  f32x16 acc[4][2];
#pragma unroll
  for (int m_ = 0; m_ < 4; ++m_)
#pragma unroll
    for (int n_ = 0; n_ < 2; ++n_)
#pragma unroll
      for (int e = 0; e < 16; ++e) acc[m_][n_][e] = 0.f;

  const int nit = (4096 >> 6) >> 1;  // 32 pairs

  // prologue: stage tiles 0 and 1 fully; drain tile0
  stageA(0, 0, 0); stageB(0, 0, 0); stageB(0, 1, 0); stageA(0, 1, 0);
  stageA(1, 0, 1); stageB(1, 0, 1); stageB(1, 1, 1); stageA(1, 1, 1);
  VMW(8);
  BAR;

  for (int i = 0; i < nit; ++i) {
    const int tb = 2 * i;
    const bool g2 = (i + 1 < nit);
    // p0: reads A00,B00 (tile tb)
    loadA32(0, 0); loadB32(0, 0, bf0);
    BAR; PRIO1; mfq32<0, 0>(acc, afr, bf0); PRIO0; BAR;
    // p1: reads B01; restage A00,B00 <- tb+2
    loadB32(0, 1, bf1);
    if (g2) { stageA(0, 0, tb + 2); stageB(0, 0, tb + 2); }
    BAR; PRIO1; mfq32<0, 1>(acc, afr, bf1); PRIO0; BAR;
    // p2: reads A01; restage B01 <- tb+2
    loadA32(0, 1);
    if (g2) stageB(0, 1, tb + 2);
    BAR; PRIO1; mfq32<1, 1>(acc, afr, bf1); PRIO0; BAR;
    // p3: B-half0 reused; restage A01 <- tb+2; counted wait
    if (g2) stageA(0, 1, tb + 2);
    BAR; PRIO1; mfq32<1, 0>(acc, afr, bf0); PRIO0;
    if (g2) { VMW(8); } else { VMW(0); }
    BAR;
    // p4: reads A10,B10 (tile tb+1)
    loadA32(1, 0); loadB32(1, 0, bf0);
    BAR; PRIO1; mfq32<0, 0>(acc, afr, bf0); PRIO0; BAR;
    // p5: reads B11; restage A10,B10 <- tb+3
    loadB32(1, 1, bf1);
    if (g2) { stageA(1, 0, tb + 3); stageB(1, 0, tb + 3); }
    BAR; PRIO1; mfq32<0, 1>(acc, afr, bf1); PRIO0; BAR;
    // p6: reads A11; restage B11 <- tb+3
    loadA32(1, 1);
    if (g2) stageB(1, 1, tb + 3);
    BAR; PRIO1; mfq32<1, 1>(acc, afr, bf1); PRIO0; BAR;
    // p7: B-half0 reused; restage A11 <- tb+3; counted wait
    if (g2) stageA(1, 1, tb + 3);
    BAR; PRIO1; mfq32<1, 0>(acc, afr, bf0); PRIO0;
    if (g2) { VMW(8); } else { }
    BAR;
  }

  // epilogue: 32x32 D layout col=l&31, row=(reg&3)+8*(reg>>2)+4*(l>>5)
#pragma unroll
  for (int am = 0; am < 4; ++am)
#pragma unroll
    for (int an = 0; an < 2; ++an) {
      const int colb = col0 + wc * 64 + an * 32 + l31;
#pragma unroll
      for (int q = 0; q < 4; ++q) {
        const int rowb = row0 + wr * 128 + am * 32 + q * 8 + l5 * 4;
#pragma unroll
        for (int rr = 0; rr < 4; ++rr)
          Cw[(size_t)(rowb + rr) * Nn + colb] = f2bf(acc[am][an][q * 4 + rr]);
      }
    }
}

// ================= 8-phase GEMM, 16x16x32 MFMA, BM=128, BN=256 (Wo, f32 out) =================
template <int MH, int NH>
__device__ __forceinline__ void mfq16(f32x4 (&acc)[4][4], const bf16x8 (&af)[2][2],
                                      const bf16x8 (&b)[2][2]) {
#pragma unroll
  for (int f = 0; f < 2; ++f)
#pragma unroll
    for (int e = 0; e < 2; ++e)
#pragma unroll
      for (int ks = 0; ks < 2; ++ks)
        acc[MH * 2 + f][NH * 2 + e] = __builtin_amdgcn_mfma_f32_16x16x32_bf16(
            af[f][ks], b[e][ks], acc[MH * 2 + f][NH * 2 + e], 0, 0, 0);
}

__global__ void __launch_bounds__(512, 2) gemm8p16(
    const u16* __restrict__ A, const u16* __restrict__ B, float* __restrict__ C) {
  __shared__ u16 As[2][2][64 * 64];
  __shared__ u16 Bs[2][2][128 * 64];
  const int t = threadIdx.x;
  const int lane = t & 63, w = t >> 6;
  const int wr = w >> 2, wc = w & 3;
  const int l15 = lane & 15, l4 = lane >> 4;

  const int flat = blockIdx.x;
  const int swz = (flat & 7) * 32 + (flat >> 3);
  const int bxt = swz & 15, byt = swz >> 4;
  const int row0 = byt * 128, col0 = bxt * 256;

  auto stageA = [&](int buf, int half, int tile) {
    const int o = t * 16;
    const int ridx = o >> 7;
    const int slot = (o >> 4) & 7;
    const int gr = (ridx >> 5) * 64 + half * 32 + (ridx & 31);
    gload_lds16(A + (size_t)(row0 + gr) * 4096 + (tile << 6) + ((slot ^ (ridx & 7)) << 3),
                (char*)&As[buf][half][0] + o);
  };
  auto stageB = [&](int buf, int half, int tile) {
#pragma unroll
    for (int g = 0; g < 2; ++g) {
      const int o = (g * 512 + t) * 16;
      const int ridx = o >> 7;
      const int slot = (o >> 4) & 7;
      const int gn = (ridx >> 5) * 64 + half * 32 + (ridx & 31);
      gload_lds16(B + (size_t)(col0 + gn) * 4096 + (tile << 6) + ((slot ^ (ridx & 7)) << 3),
                  (char*)&Bs[buf][half][0] + o);
    }
  };

  bf16x8 af[2][2], bf0[2][2], bf1[2][2];
  auto loadA = [&](int buf, int half) {
#pragma unroll
    for (int f = 0; f < 2; ++f)
#pragma unroll
      for (int ks = 0; ks < 2; ++ks) {
        const int idx = wr * 32 + f * 16 + l15;
        const int slot = ks * 4 + l4;
        af[f][ks] = *(const bf16x8*)((const char*)&As[buf][half][0] + idx * 128 +
                                     ((slot ^ (idx & 7)) << 4));
      }
  };
  auto loadB = [&](int buf, int half, bf16x8 (&dst)[2][2]) {
#pragma unroll
    for (int e = 0; e < 2; ++e)
#pragma unroll
      for (int ks = 0; ks < 2; ++ks) {
        const int idx = wc * 32 + e * 16 + l15;
        const int slot = ks * 4 + l4;
        dst[e][ks] = *(const bf16x8*)((const char*)&Bs[buf][half][0] + idx * 128 +
                                      ((slot ^ (idx & 7)) << 4));
      }
  };

  f32x4 acc[4][4];
#pragma unroll
  for (int m_ = 0; m_ < 4; ++m_)
#pragma unroll
    for (int n_ = 0; n_ < 4; ++n_) acc[m_][n_] = f32x4{0.f, 0.f, 0.f, 0.f};

  const int nit = (4096 >> 6) >> 1;

  stageA(0, 0, 0); stageB(0, 0, 0); stageB(0, 1, 0); stageA(0, 1, 0);
  stageA(1, 0, 1); stageB(1, 0, 1); stageB(1, 1, 1); stageA(1, 1, 1);
  VMW(6);
  BAR;

  for (int i = 0; i < nit; ++i) {
    const int tb = 2 * i;
    const bool g2 = (i + 1 < nit);
    // p0: reads A00,B00
    loadA(0, 0); loadB(0, 0, bf0);
    BAR; PRIO1; mfq16<0, 0>(acc, af, bf0); PRIO0; BAR;
    // p1: reads B01; restage A00,B00
    loadB(0, 1, bf1);
    if (g2) { stageA(0, 0, tb + 2); stageB(0, 0, tb + 2); }
    BAR; PRIO1; mfq16<0, 1>(acc, af, bf1); PRIO0; BAR;
    // p2: reads A01; restage B01
    loadA(0, 1);
    if (g2) stageB(0, 1, tb + 2);
    BAR; PRIO1; mfq16<1, 1>(acc, af, bf1); PRIO0; BAR;
    // p3: reuse B0; restage A01; counted wait
    if (g2) stageA(0, 1, tb + 2);
    BAR; PRIO1; mfq16<1, 0>(acc, af, bf0); PRIO0;
    if (g2) { VMW(6); } else { VMW(0); }
    BAR;
    // p4: reads A10,B10
    loadA(1, 0); loadB(1, 0, bf0);
    BAR; PRIO1; mfq16<0, 0>(acc, af, bf0); PRIO0; BAR;
    // p5: reads B11; restage A10,B10
    loadB(1, 1, bf1);
    if (g2) { stageA(1, 0, tb + 3); stageB(1, 0, tb + 3); }
    BAR; PRIO1; mfq16<0, 1>(acc, af, bf1); PRIO0; BAR;
    // p6: reads A11; restage B11
    loadA(1, 1);
    if (g2) stageB(1, 1, tb + 3);
    BAR; PRIO1; mfq16<1, 1>(acc, af, bf1); PRIO0; BAR;
    // p7: reuse B0; restage A11; counted wait
    if (g2) stageA(1, 1, tb + 3);
    BAR; PRIO1; mfq16<1, 0>(acc, af, bf0); PRIO0;
    if (g2) { VMW(6); } else { }
    BAR;
  }

#pragma unroll
  for (int am = 0; am < 4; ++am) {
    const int rowb = row0 + wr * 64 + (am >> 1) * 32 + (am & 1) * 16 + l4 * 4;
#pragma unroll
    for (int an = 0; an < 4; ++an) {
      const int colb = col0 + wc * 64 + (an >> 1) * 32 + (an & 1) * 16 + l15;
#pragma unroll
      for (int r = 0; r < 4; ++r)
        C[(size_t)(rowb + r) * 4096 + colb] = acc[am][an][r];
    }
  }
}

// ---------------- attention staging: K tile [64][128] + V^T tile [128][64], swizzled ----------------
__device__ __forceinline__ void stage_kv(const u16* __restrict__ k, const u16* __restrict__ vt,
                                         const int kvh, const int kv0, u16* KsB, u16* VsB,
                                         const int t) {
#pragma unroll
  for (int i = 0; i < 4; ++i) {
    const int o = (i * 256 + t) * 16;
    const int row = o >> 8;
    const int slot = (o >> 4) & 15;
    gload_lds16(k + (size_t)(kv0 + row) * (NKVH * HD) + kvh * HD + ((slot ^ (row & 7)) << 3),
                (char*)KsB + o);
  }
#pragma unroll
  for (int i = 0; i < 4; ++i) {
    const int o = (i * 256 + t) * 16;
    const int row = o >> 7;
    const int slot = (o >> 4) & 7;
    gload_lds16(vt + (size_t)(kvh * HD + row) * SEQ + kv0 + ((slot ^ (row & 7)) << 3),
                (char*)VsB + o);
  }
}

// ---------------- causal GQA flash attention, swapped-QK in-register softmax ----------------
__global__ void __launch_bounds__(256) attn_fwd(const u16* __restrict__ q, const u16* __restrict__ k,
                                                const u16* __restrict__ vt, u16* __restrict__ ctx) {
  __shared__ u16 Ks[2][64 * 128];
  __shared__ u16 Vs[2][128 * 64];
  const int t = threadIdx.x, lane = t & 63, w = t >> 6;
  const int h = blockIdx.x;
  const int qb = (int)gridDim.y - 1 - (int)blockIdx.y;
  const int kvh = h >> 2;
  const int q0 = qb * 64;
  const int sq_base = q0 + w * 16;
  const int l15 = lane & 15, l4 = lane >> 4;
  const int sq_abs = sq_base + l15;

  bf16x8 qf[4];
  {
    const u16* qp = q + (size_t)sq_abs * (NHEADS * HD) + h * HD + l4 * 8;
#pragma unroll
    for (int kb = 0; kb < 4; ++kb) qf[kb] = *(const bf16x8*)(qp + kb * 32);
  }
  f32x4 po[8];
#pragma unroll
  for (int i = 0; i < 8; ++i) po[i] = f32x4{0.f, 0.f, 0.f, 0.f};
  float mrow = -1e30f;
  float lrow = 0.f;

  const int nb = qb + 1;
  stage_kv(k, vt, kvh, 0, Ks[0], Vs[0], t);
  __syncthreads();
  int cur = 0;

  for (int b = 0; b < nb; ++b) {
    if (b + 1 < nb) stage_kv(k, vt, kvh, (b + 1) * 64, Ks[cur ^ 1], Vs[cur ^ 1], t);

    f32x4 st[4];
#pragma unroll
    for (int c = 0; c < 4; ++c) st[c] = f32x4{0.f, 0.f, 0.f, 0.f};
#pragma unroll
    for (int c = 0; c < 4; ++c) {
      const int row = c * 16 + l15;
#pragma unroll
      for (int kb = 0; kb < 4; ++kb) {
        const int slot = kb * 4 + l4;
        bf16x8 bk = *(const bf16x8*)((const char*)Ks[cur] + row * 256 + ((slot ^ (row & 7)) << 4));
        st[c] = __builtin_amdgcn_mfma_f32_16x16x32_bf16(bk, qf[kb], st[c], 0, 0, 0);
      }
    }

    if (b == nb - 1) {
#pragma unroll
      for (int c = 0; c < 4; ++c)
#pragma unroll
        for (int r = 0; r < 4; ++r) {
          const int sk = b * 64 + c * 16 + l4 * 4 + r;
          if (sk > sq_abs) st[c][r] = -1e30f;
        }
    }

    float rmax = -3e38f;
#pragma unroll
    for (int c = 0; c < 4; ++c)
      rmax = fmaxf(rmax, fmaxf(fmaxf(st[c][0], st[c][1]), fmaxf(st[c][2], st[c][3])));
    rmax = fmaxf(rmax, __shfl_xor(rmax, 16, 64));
    rmax = fmaxf(rmax, __shfl_xor(rmax, 32, 64));

    const bool skip = __all(rmax <= mrow + 8.f);
    const float mnew = skip ? mrow : fmaxf(mrow, rmax);

    float rs = 0.f;
#pragma unroll
    for (int c = 0; c < 4; ++c) {
      const float e0 = exp2f(st[c][0] - mnew), e1 = exp2f(st[c][1] - mnew);
      const float e2 = exp2f(st[c][2] - mnew), e3 = exp2f(st[c][3] - mnew);
      st[c][0] = e0; st[c][1] = e1; st[c][2] = e2; st[c][3] = e3;
      rs += (e0 + e1) + (e2 + e3);
    }
    rs += __shfl_xor(rs, 16, 64);
    rs += __shfl_xor(rs, 32, 64);

    if (!skip) {
      const float alpha = exp2f(mrow - mnew);
      mrow = mnew;
      lrow = lrow * alpha + rs;
      float av[4];
#pragma unroll
      for (int r = 0; r < 4; ++r) av[r] = __shfl(alpha, l4 * 4 + r, 16);
#pragma unroll
      for (int db = 0; db < 8; ++db)
#pragma unroll
        for (int r = 0; r < 4; ++r) po[db][r] *= av[r];
    } else {
      lrow += rs;
    }

    u32 pk[4][2];
#pragma unroll
    for (int c = 0; c < 4; ++c) {
      pk[c][0] = (u32)f2bf(st[c][0]) | ((u32)f2bf(st[c][1]) << 16);
      pk[c][1] = (u32)f2bf(st[c][2]) | ((u32)f2bf(st[c][3]) << 16);
    }
    const int src01 = l15 + ((lane & 16) << 1);
    const int src23 = src01 + 16;
    const bool lo = (lane & 32) == 0;
#pragma unroll
    for (int kb2 = 0; kb2 < 2; ++kb2) {
      const int c0 = kb2 * 2, c1 = c0 + 1;
      const u32 a0 = (u32)__shfl((int)pk[c0][0], src01, 64);
      const u32 a1 = (u32)__shfl((int)pk[c0][1], src01, 64);
      const u32 a2 = (u32)__shfl((int)pk[c0][0], src23, 64);
      const u32 a3 = (u32)__shfl((int)pk[c0][1], src23, 64);
      const u32 b0 = (u32)__shfl((int)pk[c1][0], src01, 64);
      const u32 b1 = (u32)__shfl((int)pk[c1][1], src01, 64);
      const u32 b2 = (u32)__shfl((int)pk[c1][0], src23, 64);
      const u32 b3 = (u32)__shfl((int)pk[c1][1], src23, 64);
      u32x4 wq;
      wq.x = lo ? a0 : b0;
      wq.y = lo ? a1 : b1;
      wq.z = lo ? a2 : b2;
      wq.w = lo ? a3 : b3;
      const bf16x8 pa = __builtin_bit_cast(bf16x8, wq);
#pragma unroll
      for (int db = 0; db < 8; ++db) {
        const int vrow = db * 16 + l15;
        const int pslot = kb2 * 4 + l4;
        bf16x8 bv = *(const bf16x8*)((const char*)Vs[cur] + vrow * 128 + ((pslot ^ (vrow & 7)) << 4));
        po[db] = __builtin_amdgcn_mfma_f32_16x16x32_bf16(pa, bv, po[db], 0, 0, 0);
      }
    }
    __syncthreads();
    cur ^= 1;
  }

  float rl[4];
#pragma unroll
  for (int r = 0; r < 4; ++r) rl[r] = 1.f / __shfl(lrow, l4 * 4 + r, 16);
#pragma unroll
  for (int db = 0; db < 8; ++db)
#pragma unroll
    for (int r = 0; r < 4; ++r) {
      const int sq = sq_base + l4 * 4 + r;
      const int d = db * 16 + l15;
      ctx[(size_t)sq * (NHEADS * HD) + h * HD + d] = f2bf(po[db][r] * rl[r]);
    }
}

extern "C" void kernel_launch(void* const* d_in, const int* in_sizes, int n_in,
                              void* d_out, int out_size, void* d_ws, size_t ws_size,
                              hipStream_t stream) {
  const float* hs = (const float*)d_in[0];
  const int* pos = (const int*)d_in[1];
  const float* Wq = (const float*)d_in[2];
  const float* Wk = (const float*)d_in[3];
  const float* Wv = (const float*)d_in[4];
  const float* Wo = (const float*)d_in[5];

  u16* ws = (u16*)d_ws;
  u16* Xb = ws;                                   // [2048][4096]
  u16* Wqt = Xb + (size_t)2048 * 4096;            // [4096][4096]
  u16* Wkt = Wqt + (size_t)4096 * 4096;           // [1024][4096]
  u16* Wvt = Wkt + (size_t)1024 * 4096;           // [1024][4096]
  u16* Wot = Wvt + (size_t)1024 * 4096;           // [4096][4096]
  u16* qb = Wot + (size_t)4096 * 4096;            // [2048][4096]
  u16* kb = qb + (size_t)2048 * 4096;             // [2048][1024]
  u16* vb = kb + (size_t)2048 * 1024;             // [2048][1024]
  u16* vtb = vb + (size_t)2048 * 1024;            // [1024][2048]
  u16* ctx = vtb + (size_t)1024 * 2048;           // [2048][4096]
  const size_t need = ((size_t)(ctx - ws) + (size_t)2048 * 4096) * 2;
  if (ws_size < need) return;

  // fused X conversion + Wq/Wk/Wv transposes
  prep_all<<<14336, 256, 0, stream>>>(hs, Xb, Wq, Wqt, Wk, Wkt, Wv, Wvt);

  // fused Q+K+V projections (192 gemm blocks) + folded Wo transpose (64 blocks)
  gemm8p32<<<256, 512, 0, stream>>>(Xb, Wqt, Wkt, Wvt, qb, kb, vb, Wo, Wot);

  // fused RoPE(q) + RoPE(k) + V transpose
  post_qkv<<<22528, 256, 0, stream>>>(qb, kb, vb, vtb, pos);

  attn_fwd<<<dim3(32, 32), 256, 0, stream>>>(qb, kb, vtb, ctx);

  // output projection -> fp32 d_out
  gemm8p16<<<256, 512, 0, stream>>>(ctx, Wot, (float*)d_out);
}

// Round 7
// 344.144 us; speedup vs baseline: 1.1945x; 1.0064x over previous
//
#include <hip/hip_runtime.h>
#include <hip/hip_bf16.h>
#include <math.h>

#define SEQ 2048
#define NHEADS 32
#define NKVH 8
#define HD 128
#define HIDDEN 4096

typedef unsigned short u16;
typedef unsigned int u32;
typedef __attribute__((ext_vector_type(8))) __bf16 bf16x8;
typedef __attribute__((ext_vector_type(4))) float f32x4;
typedef __attribute__((ext_vector_type(16))) float f32x16;
typedef __attribute__((ext_vector_type(4))) u16 u16x4;
typedef __attribute__((ext_vector_type(4))) u32 u32x4;

__device__ __forceinline__ u16 f2bf(float f) {
  u32 u = __builtin_bit_cast(u32, f);
  u32 r = (u + 0x7fffu + ((u >> 16) & 1u)) >> 16;
  return (u16)r;
}
__device__ __forceinline__ float bf2f(u16 h) {
  return __builtin_bit_cast(float, ((u32)h) << 16);
}
__device__ __forceinline__ void gload_lds16(const void* g, void* l) {
  __builtin_amdgcn_global_load_lds(
      (const __attribute__((address_space(1))) u32*)g,
      (__attribute__((address_space(3))) u32*)l, 16, 0, 0);
}

#define BAR __builtin_amdgcn_s_barrier()
#define PRIO1 __builtin_amdgcn_s_setprio(1)
#define PRIO0 __builtin_amdgcn_s_setprio(0)
#define VMW(n) asm volatile("s_waitcnt vmcnt(" #n ")" ::: "memory")

// ---------------- fused prep: X f32->bf16 + Wq/Wk/Wv transpose f32->bf16^T ----------------
__global__ void __launch_bounds__(256) prep_all(
    const float* __restrict__ hs, u16* __restrict__ Xb,
    const float* __restrict__ Wq, u16* __restrict__ Wqt,
    const float* __restrict__ Wk, u16* __restrict__ Wkt,
    const float* __restrict__ Wv, u16* __restrict__ Wvt) {
  const int bid = blockIdx.x;
  if (bid < 8192) {  // X conversion, 4 f32/thread
    const int i = (bid * 256 + threadIdx.x) * 4;
    const float4 v = *(const float4*)(hs + i);
    u16x4 o;
    o.x = f2bf(v.x); o.y = f2bf(v.y); o.z = f2bf(v.z); o.w = f2bf(v.w);
    *(u16x4*)(Xb + i) = o;
    return;
  }
  __shared__ float tile[64][65];
  const float* src; u16* dst; int C, lc, tb;
  const int b2 = bid - 8192;
  if (b2 < 4096) { src = Wq; dst = Wqt; C = 4096; lc = 6; tb = b2; }
  else if (b2 < 5120) { src = Wk; dst = Wkt; C = 1024; lc = 4; tb = b2 - 4096; }
  else { src = Wv; dst = Wvt; C = 1024; lc = 4; tb = b2 - 5120; }
  const int r0 = (tb >> lc) * 64, c0 = (tb & ((1 << lc) - 1)) * 64;
  const int tx = threadIdx.x & 63, ty = threadIdx.x >> 6;
#pragma unroll
  for (int j = 0; j < 16; ++j)
    tile[ty + j * 4][tx] = src[(size_t)(r0 + ty + j * 4) * C + c0 + tx];
  __syncthreads();
#pragma unroll
  for (int j = 0; j < 16; ++j)
    dst[(size_t)(c0 + ty + j * 4) * 4096 + r0 + tx] = f2bf(tile[tx][ty + j * 4]);
}

// ---------------- fused post-QKV: RoPE(q)+RoPE(k) + V transpose ----------------
__global__ void __launch_bounds__(256) post_qkv(u16* __restrict__ qb, u16* __restrict__ kb,
                                                const u16* __restrict__ vb, u16* __restrict__ vtb,
                                                const int* __restrict__ pos) {
  const int bid = blockIdx.x;
  if (bid < 20480) {  // RoPE
    u16* x; int lognh; float oscale;
    int idx;
    if (bid < 16384) {
      x = qb; lognh = 5;
      oscale = 0.08838834764831845f * 1.44269504088896340f;  // 1/sqrt(128)*log2(e)
      idx = bid * 256 + threadIdx.x;
    } else {
      x = kb; lognh = 3; oscale = 1.0f;
      idx = (bid - 16384) * 256 + threadIdx.x;
    }
    const int j = idx & 63;
    const int hh = (idx >> 6) & ((1 << lognh) - 1);
    const int s = idx >> (6 + lognh);
    if (s >= SEQ) return;
    const float p = (float)pos[s];
    const float invf = __expf((float)j * -0.14391156831212787f);  // -ln(10000)/64
    const float ang = p * invf;
    const float c = cosf(ang), sn = sinf(ang);
    u16* bp = x + ((size_t)s << (7 + lognh)) + hh * 128 + j;
    const float x1 = bf2f(bp[0]), x2 = bf2f(bp[64]);
    bp[0] = f2bf((x1 * c - x2 * sn) * oscale);
    bp[64] = f2bf((x2 * c + x1 * sn) * oscale);
    return;
  }
  // V transpose: vb [2048][1024] -> vtb [1024][2048]
  __shared__ u16 tile[32][34];
  const int b2 = bid - 20480;
  const int c0 = (b2 & 31) * 32, r0 = (b2 >> 5) * 32;
  const int tx = threadIdx.x & 31, ty = threadIdx.x >> 5;
#pragma unroll
  for (int i = 0; i < 4; ++i)
    tile[ty + i * 8][tx] = vb[(size_t)(r0 + ty + i * 8) * 1024 + c0 + tx];
  __syncthreads();
#pragma unroll
  for (int i = 0; i < 4; ++i)
    vtb[(size_t)(c0 + ty + i * 8) * 2048 + r0 + tx] = tile[tx][ty + i * 8];
}

// ================= 8-phase GEMM, 32x32x16 MFMA, BM=BN=256, BK=64 =================
// Row-panel-per-XCD mapping: XCD x owns row-tile byt=x (A panel 2MB L2-resident)
// x 24 col-tiles, + 8 folded-transpose blocks per XCD.
template <int MH, int NH>
__device__ __forceinline__ void mfq32(f32x16 (&acc)[4][2], const bf16x8 (&afr)[2][4],
                                      const bf16x8 (&b)[4]) {
#pragma unroll
  for (int f = 0; f < 2; ++f)
#pragma unroll
    for (int ks = 0; ks < 4; ++ks)
      acc[MH * 2 + f][NH] = __builtin_amdgcn_mfma_f32_32x32x16_bf16(
          afr[f][ks], b[ks], acc[MH * 2 + f][NH], 0, 0, 0);
}

__global__ void __launch_bounds__(512, 2) gemm8p32(
    const u16* __restrict__ A, const u16* __restrict__ B0q, const u16* __restrict__ B1q,
    const u16* __restrict__ B2q, u16* __restrict__ C0, u16* __restrict__ C1,
    u16* __restrict__ C2, const float* __restrict__ Wsrc, u16* __restrict__ Wdst) {
  __shared__ u16 As[2][2][128 * 64];
  __shared__ u16 Bs[2][2][128 * 64];
  const int t = threadIdx.x;
  const int flat = blockIdx.x;
  const int xcd = flat & 7, idx = flat >> 3;  // 8 XCDs x 32 slots

  if (idx >= 24) {  // ---- folded Wo transpose (f32 [4096][4096] -> bf16^T), 8 blocks/XCD ----
    const int wid = xcd * 8 + (idx - 24);  // 0..63, rows [wid*64, +64)
    float* tf = (float*)&As[0][0][0];
    const int tx = t & 63, ty = t >> 6;
    const int r0 = wid * 64;
    for (int ct = 0; ct < 64; ++ct) {
      const int c0 = ct * 64;
#pragma unroll
      for (int i = 0; i < 8; ++i)
        tf[(ty + i * 8) * 65 + tx] = Wsrc[(size_t)(r0 + ty + i * 8) * 4096 + c0 + tx];
      __syncthreads();
#pragma unroll
      for (int i = 0; i < 8; ++i)
        Wdst[(size_t)(c0 + ty + i * 8) * 4096 + r0 + tx] = f2bf(tf[tx * 65 + ty + i * 8]);
      __syncthreads();
    }
    return;
  }

  const int lane = t & 63, w = t >> 6;
  const int wr = w >> 2, wc = w & 3;
  const int l31 = lane & 31, l5 = lane >> 5;

  int bxt = idx;            // 0..23: col tile (B-panel streams via LLC)
  const int byt = xcd;      // row tile: A panel L2-resident per XCD
  const u16* Bp; u16* Cw; int Nn;
  if (bxt < 16) { Bp = B0q; Cw = C0; Nn = 4096; }
  else if (bxt < 20) { bxt -= 16; Bp = B1q; Cw = C1; Nn = 1024; }
  else { bxt -= 20; Bp = B2q; Cw = C2; Nn = 1024; }
  const int row0 = byt * 256, col0 = bxt * 256;

  auto stageA = [&](int buf, int half, int tile) {
#pragma unroll
    for (int g = 0; g < 2; ++g) {
      const int o = (g * 512 + t) * 16;
      const int ridx = o >> 7;
      const int slot = (o >> 4) & 7;
      const int gr = (ridx >> 6) * 128 + half * 64 + (ridx & 63);
      gload_lds16(A + (size_t)(row0 + gr) * 4096 + (tile << 6) + ((slot ^ (ridx & 7)) << 3),
                  (char*)&As[buf][half][0] + o);
    }
  };
  auto stageB = [&](int buf, int half, int tile) {
#pragma unroll
    for (int g = 0; g < 2; ++g) {
      const int o = (g * 512 + t) * 16;
      const int ridx = o >> 7;
      const int slot = (o >> 4) & 7;
      const int gn = (ridx >> 5) * 64 + half * 32 + (ridx & 31);
      gload_lds16(Bp + (size_t)(col0 + gn) * 4096 + (tile << 6) + ((slot ^ (ridx & 7)) << 3),
                  (char*)&Bs[buf][half][0] + o);
    }
  };

  bf16x8 afr[2][4], bf0[4], bf1[4];
  auto loadA32 = [&](int buf, int half) {
#pragma unroll
    for (int f = 0; f < 2; ++f)
#pragma unroll
      for (int ks = 0; ks < 4; ++ks) {
        const int idx2 = wr * 64 + f * 32 + l31;
        const int slot = ks * 2 + l5;
        afr[f][ks] = *(const bf16x8*)((const char*)&As[buf][half][0] + idx2 * 128 +
                                      ((slot ^ (idx2 & 7)) << 4));
      }
  };
  auto loadB32 = [&](int buf, int half, bf16x8 (&dst)[4]) {
#pragma unroll
    for (int ks = 0; ks < 4; ++ks) {
      const int idx2 = wc * 32 + l31;
      const int slot = ks * 2 + l5;
      dst[ks] = *(const bf16x8*)((const char*)&Bs[buf][half][0] + idx2 * 128 +
                                 ((slot ^ (idx2 & 7)) << 4));
    }
  };

  f32x16 acc[4][2];
#pragma unroll
  for (int m_ = 0; m_ < 4; ++m_)
#pragma unroll
    for (int n_ = 0; n_ < 2; ++n_)
#pragma unroll
      for (int e = 0; e < 16; ++e) acc[m_][n_][e] = 0.f;

  const int nit = (4096 >> 6) >> 1;  // 32 pairs

  // prologue: stage tiles 0 and 1 fully; drain tile0
  stageA(0, 0, 0); stageB(0, 0, 0); stageB(0, 1, 0); stageA(0, 1, 0);
  stageA(1, 0, 1); stageB(1, 0, 1); stageB(1, 1, 1); stageA(1, 1, 1);
  VMW(8);
  BAR;

  for (int i = 0; i < nit; ++i) {
    const int tb = 2 * i;
    const bool g2 = (i + 1 < nit);
    // p0: reads A00,B00 (tile tb)
    loadA32(0, 0); loadB32(0, 0, bf0);
    BAR; PRIO1; mfq32<0, 0>(acc, afr, bf0); PRIO0; BAR;
    // p1: reads B01; restage A00,B00 <- tb+2
    loadB32(0, 1, bf1);
    if (g2) { stageA(0, 0, tb + 2); stageB(0, 0, tb + 2); }
    BAR; PRIO1; mfq32<0, 1>(acc, afr, bf1); PRIO0; BAR;
    // p2: reads A01; restage B01 <- tb+2
    loadA32(0, 1);
    if (g2) stageB(0, 1, tb + 2);
    BAR; PRIO1; mfq32<1, 1>(acc, afr, bf1); PRIO0; BAR;
    // p3: B-half0 reused; restage A01 <- tb+2; counted wait
    if (g2) stageA(0, 1, tb + 2);
    BAR; PRIO1; mfq32<1, 0>(acc, afr, bf0); PRIO0;
    if (g2) { VMW(8); } else { VMW(0); }
    BAR;
    // p4: reads A10,B10 (tile tb+1)
    loadA32(1, 0); loadB32(1, 0, bf0);
    BAR; PRIO1; mfq32<0, 0>(acc, afr, bf0); PRIO0; BAR;
    // p5: reads B11; restage A10,B10 <- tb+3
    loadB32(1, 1, bf1);
    if (g2) { stageA(1, 0, tb + 3); stageB(1, 0, tb + 3); }
    BAR; PRIO1; mfq32<0, 1>(acc, afr, bf1); PRIO0; BAR;
    // p6: reads A11; restage B11 <- tb+3
    loadA32(1, 1);
    if (g2) stageB(1, 1, tb + 3);
    BAR; PRIO1; mfq32<1, 1>(acc, afr, bf1); PRIO0; BAR;
    // p7: B-half0 reused; restage A11 <- tb+3; counted wait
    if (g2) stageA(1, 1, tb + 3);
    BAR; PRIO1; mfq32<1, 0>(acc, afr, bf0); PRIO0;
    if (g2) { VMW(8); } else { }
    BAR;
  }

  // epilogue: 32x32 D layout col=l&31, row=(reg&3)+8*(reg>>2)+4*(l>>5)
#pragma unroll
  for (int am = 0; am < 4; ++am)
#pragma unroll
    for (int an = 0; an < 2; ++an) {
      const int colb = col0 + wc * 64 + an * 32 + l31;
#pragma unroll
      for (int q = 0; q < 4; ++q) {
        const int rowb = row0 + wr * 128 + am * 32 + q * 8 + l5 * 4;
#pragma unroll
        for (int rr = 0; rr < 4; ++rr)
          Cw[(size_t)(rowb + rr) * Nn + colb] = f2bf(acc[am][an][q * 4 + rr]);
      }
    }
}

// ================= 8-phase GEMM, 16x16x32 MFMA, BM=128, BN=256 (Wo, f32 out) =================
template <int MH, int NH>
__device__ __forceinline__ void mfq16(f32x4 (&acc)[4][4], const bf16x8 (&af)[2][2],
                                      const bf16x8 (&b)[2][2]) {
#pragma unroll
  for (int f = 0; f < 2; ++f)
#pragma unroll
    for (int e = 0; e < 2; ++e)
#pragma unroll
      for (int ks = 0; ks < 2; ++ks)
        acc[MH * 2 + f][NH * 2 + e] = __builtin_amdgcn_mfma_f32_16x16x32_bf16(
            af[f][ks], b[e][ks], acc[MH * 2 + f][NH * 2 + e], 0, 0, 0);
}

__global__ void __launch_bounds__(512, 2) gemm8p16(
    const u16* __restrict__ A, const u16* __restrict__ B, float* __restrict__ C) {
  __shared__ u16 As[2][2][64 * 64];
  __shared__ u16 Bs[2][2][128 * 64];
  const int t = threadIdx.x;
  const int lane = t & 63, w = t >> 6;
  const int wr = w >> 2, wc = w & 3;
  const int l15 = lane & 15, l4 = lane >> 4;

  const int flat = blockIdx.x;
  const int xcd = flat & 7, idx = flat >> 3;         // 32 blocks per XCD
  const int bxt = idx & 15, byt = xcd * 2 + (idx >> 4);  // 2 row-panels per XCD (2MB L2)
  const int row0 = byt * 128, col0 = bxt * 256;

  auto stageA = [&](int buf, int half, int tile) {
    const int o = t * 16;
    const int ridx = o >> 7;
    const int slot = (o >> 4) & 7;
    const int gr = (ridx >> 5) * 64 + half * 32 + (ridx & 31);
    gload_lds16(A + (size_t)(row0 + gr) * 4096 + (tile << 6) + ((slot ^ (ridx & 7)) << 3),
                (char*)&As[buf][half][0] + o);
  };
  auto stageB = [&](int buf, int half, int tile) {
#pragma unroll
    for (int g = 0; g < 2; ++g) {
      const int o = (g * 512 + t) * 16;
      const int ridx = o >> 7;
      const int slot = (o >> 4) & 7;
      const int gn = (ridx >> 5) * 64 + half * 32 + (ridx & 31);
      gload_lds16(B + (size_t)(col0 + gn) * 4096 + (tile << 6) + ((slot ^ (ridx & 7)) << 3),
                  (char*)&Bs[buf][half][0] + o);
    }
  };

  bf16x8 af[2][2], bf0[2][2], bf1[2][2];
  auto loadA = [&](int buf, int half) {
#pragma unroll
    for (int f = 0; f < 2; ++f)
#pragma unroll
      for (int ks = 0; ks < 2; ++ks) {
        const int idx2 = wr * 32 + f * 16 + l15;
        const int slot = ks * 4 + l4;
        af[f][ks] = *(const bf16x8*)((const char*)&As[buf][half][0] + idx2 * 128 +
                                     ((slot ^ (idx2 & 7)) << 4));
      }
  };
  auto loadB = [&](int buf, int half, bf16x8 (&dst)[2][2]) {
#pragma unroll
    for (int e = 0; e < 2; ++e)
#pragma unroll
      for (int ks = 0; ks < 2; ++ks) {
        const int idx2 = wc * 32 + e * 16 + l15;
        const int slot = ks * 4 + l4;
        dst[e][ks] = *(const bf16x8*)((const char*)&Bs[buf][half][0] + idx2 * 128 +
                                      ((slot ^ (idx2 & 7)) << 4));
      }
  };

  f32x4 acc[4][4];
#pragma unroll
  for (int m_ = 0; m_ < 4; ++m_)
#pragma unroll
    for (int n_ = 0; n_ < 4; ++n_) acc[m_][n_] = f32x4{0.f, 0.f, 0.f, 0.f};

  const int nit = (4096 >> 6) >> 1;

  stageA(0, 0, 0); stageB(0, 0, 0); stageB(0, 1, 0); stageA(0, 1, 0);
  stageA(1, 0, 1); stageB(1, 0, 1); stageB(1, 1, 1); stageA(1, 1, 1);
  VMW(6);
  BAR;

  for (int i = 0; i < nit; ++i) {
    const int tb = 2 * i;
    const bool g2 = (i + 1 < nit);
    // p0: reads A00,B00
    loadA(0, 0); loadB(0, 0, bf0);
    BAR; PRIO1; mfq16<0, 0>(acc, af, bf0); PRIO0; BAR;
    // p1: reads B01; restage A00,B00
    loadB(0, 1, bf1);
    if (g2) { stageA(0, 0, tb + 2); stageB(0, 0, tb + 2); }
    BAR; PRIO1; mfq16<0, 1>(acc, af, bf1); PRIO0; BAR;
    // p2: reads A01; restage B01
    loadA(0, 1);
    if (g2) stageB(0, 1, tb + 2);
    BAR; PRIO1; mfq16<1, 1>(acc, af, bf1); PRIO0; BAR;
    // p3: reuse B0; restage A01; counted wait
    if (g2) stageA(0, 1, tb + 2);
    BAR; PRIO1; mfq16<1, 0>(acc, af, bf0); PRIO0;
    if (g2) { VMW(6); } else { VMW(0); }
    BAR;
    // p4: reads A10,B10
    loadA(1, 0); loadB(1, 0, bf0);
    BAR; PRIO1; mfq16<0, 0>(acc, af, bf0); PRIO0; BAR;
    // p5: reads B11; restage A10,B10
    loadB(1, 1, bf1);
    if (g2) { stageA(1, 0, tb + 3); stageB(1, 0, tb + 3); }
    BAR; PRIO1; mfq16<0, 1>(acc, af, bf1); PRIO0; BAR;
    // p6: reads A11; restage B11
    loadA(1, 1);
    if (g2) stageB(1, 1, tb + 3);
    BAR; PRIO1; mfq16<1, 1>(acc, af, bf1); PRIO0; BAR;
    // p7: reuse B0; restage A11; counted wait
    if (g2) stageA(1, 1, tb + 3);
    BAR; PRIO1; mfq16<1, 0>(acc, af, bf0); PRIO0;
    if (g2) { VMW(6); } else { }
    BAR;
  }

#pragma unroll
  for (int am = 0; am < 4; ++am) {
    const int rowb = row0 + wr * 64 + (am >> 1) * 32 + (am & 1) * 16 + l4 * 4;
#pragma unroll
    for (int an = 0; an < 4; ++an) {
      const int colb = col0 + wc * 64 + (an >> 1) * 32 + (an & 1) * 16 + l15;
#pragma unroll
      for (int r = 0; r < 4; ++r)
        C[(size_t)(rowb + r) * 4096 + colb] = acc[am][an][r];
    }
  }
}

// ---------------- attention staging: K tile [64][128] + V^T tile [128][64], swizzled ----------------
__device__ __forceinline__ void stage_kv(const u16* __restrict__ k, const u16* __restrict__ vt,
                                         const int kvh, const int kv0, u16* KsB, u16* VsB,
                                         const int t) {
#pragma unroll
  for (int i = 0; i < 4; ++i) {
    const int o = (i * 256 + t) * 16;
    const int row = o >> 8;
    const int slot = (o >> 4) & 15;
    gload_lds16(k + (size_t)(kv0 + row) * (NKVH * HD) + kvh * HD + ((slot ^ (row & 7)) << 3),
                (char*)KsB + o);
  }
#pragma unroll
  for (int i = 0; i < 4; ++i) {
    const int o = (i * 256 + t) * 16;
    const int row = o >> 7;
    const int slot = (o >> 4) & 7;
    gload_lds16(vt + (size_t)(kvh * HD + row) * SEQ + kv0 + ((slot ^ (row & 7)) << 3),
                (char*)VsB + o);
  }
}

// ---------------- causal GQA flash attention, swapped-QK in-register softmax ----------------
// kv-head-per-XCD mapping: blocks of one kv group land on one XCD -> K/V (1MB) L2-resident.
__global__ void __launch_bounds__(256) attn_fwd(const u16* __restrict__ q, const u16* __restrict__ k,
                                                const u16* __restrict__ vt, u16* __restrict__ ctx) {
  __shared__ u16 Ks[2][64 * 128];
  __shared__ u16 Vs[2][128 * 64];
  const int t = threadIdx.x, lane = t & 63, w = t >> 6;
  const int bid = blockIdx.x;
  const int xcd = bid & 7, bi = bid >> 3;      // 128 blocks per XCD
  const int h = xcd * 4 + (bi & 3);            // kvh = xcd
  const int qb = 31 - (bi >> 2);               // long blocks first
  const int kvh = xcd;
  const int q0 = qb * 64;
  const int sq_base = q0 + w * 16;
  const int l15 = lane & 15, l4 = lane >> 4;
  const int sq_abs = sq_base + l15;

  bf16x8 qf[4];
  {
    const u16* qp = q + (size_t)sq_abs * (NHEADS * HD) + h * HD + l4 * 8;
#pragma unroll
    for (int kb = 0; kb < 4; ++kb) qf[kb] = *(const bf16x8*)(qp + kb * 32);
  }
  f32x4 po[8];
#pragma unroll
  for (int i = 0; i < 8; ++i) po[i] = f32x4{0.f, 0.f, 0.f, 0.f};
  float mrow = -1e30f;
  float lrow = 0.f;

  const int nb = qb + 1;
  stage_kv(k, vt, kvh, 0, Ks[0], Vs[0], t);
  __syncthreads();
  int cur = 0;

  for (int b = 0; b < nb; ++b) {
    if (b + 1 < nb) stage_kv(k, vt, kvh, (b + 1) * 64, Ks[cur ^ 1], Vs[cur ^ 1], t);

    f32x4 st[4];
#pragma unroll
    for (int c = 0; c < 4; ++c) st[c] = f32x4{0.f, 0.f, 0.f, 0.f};
#pragma unroll
    for (int c = 0; c < 4; ++c) {
      const int row = c * 16 + l15;
#pragma unroll
      for (int kb = 0; kb < 4; ++kb) {
        const int slot = kb * 4 + l4;
        bf16x8 bk = *(const bf16x8*)((const char*)Ks[cur] + row * 256 + ((slot ^ (row & 7)) << 4));
        st[c] = __builtin_amdgcn_mfma_f32_16x16x32_bf16(bk, qf[kb], st[c], 0, 0, 0);
      }
    }

    if (b == nb - 1) {
#pragma unroll
      for (int c = 0; c < 4; ++c)
#pragma unroll
        for (int r = 0; r < 4; ++r) {
          const int sk = b * 64 + c * 16 + l4 * 4 + r;
          if (sk > sq_abs) st[c][r] = -1e30f;
        }
    }

    float rmax = -3e38f;
#pragma unroll
    for (int c = 0; c < 4; ++c)
      rmax = fmaxf(rmax, fmaxf(fmaxf(st[c][0], st[c][1]), fmaxf(st[c][2], st[c][3])));
    rmax = fmaxf(rmax, __shfl_xor(rmax, 16, 64));
    rmax = fmaxf(rmax, __shfl_xor(rmax, 32, 64));

    const bool skip = __all(rmax <= mrow + 8.f);
    const float mnew = skip ? mrow : fmaxf(mrow, rmax);

    float rs = 0.f;
#pragma unroll
    for (int c = 0; c < 4; ++c) {
      const float e0 = exp2f(st[c][0] - mnew), e1 = exp2f(st[c][1] - mnew);
      const float e2 = exp2f(st[c][2] - mnew), e3 = exp2f(st[c][3] - mnew);
      st[c][0] = e0; st[c][1] = e1; st[c][2] = e2; st[c][3] = e3;
      rs += (e0 + e1) + (e2 + e3);
    }
    rs += __shfl_xor(rs, 16, 64);
    rs += __shfl_xor(rs, 32, 64);

    if (!skip) {
      const float alpha = exp2f(mrow - mnew);
      mrow = mnew;
      lrow = lrow * alpha + rs;
      float av[4];
#pragma unroll
      for (int r = 0; r < 4; ++r) av[r] = __shfl(alpha, l4 * 4 + r, 16);
#pragma unroll
      for (int db = 0; db < 8; ++db)
#pragma unroll
        for (int r = 0; r < 4; ++r) po[db][r] *= av[r];
    } else {
      lrow += rs;
    }

    u32 pk[4][2];
#pragma unroll
    for (int c = 0; c < 4; ++c) {
      pk[c][0] = (u32)f2bf(st[c][0]) | ((u32)f2bf(st[c][1]) << 16);
      pk[c][1] = (u32)f2bf(st[c][2]) | ((u32)f2bf(st[c][3]) << 16);
    }
    const int src01 = l15 + ((lane & 16) << 1);
    const int src23 = src01 + 16;
    const bool lo = (lane & 32) == 0;
#pragma unroll
    for (int kb2 = 0; kb2 < 2; ++kb2) {
      const int c0 = kb2 * 2, c1 = c0 + 1;
      const u32 a0 = (u32)__shfl((int)pk[c0][0], src01, 64);
      const u32 a1 = (u32)__shfl((int)pk[c0][1], src01, 64);
      const u32 a2 = (u32)__shfl((int)pk[c0][0], src23, 64);
      const u32 a3 = (u32)__shfl((int)pk[c0][1], src23, 64);
      const u32 b0 = (u32)__shfl((int)pk[c1][0], src01, 64);
      const u32 b1 = (u32)__shfl((int)pk[c1][1], src01, 64);
      const u32 b2 = (u32)__shfl((int)pk[c1][0], src23, 64);
      const u32 b3 = (u32)__shfl((int)pk[c1][1], src23, 64);
      u32x4 wq;
      wq.x = lo ? a0 : b0;
      wq.y = lo ? a1 : b1;
      wq.z = lo ? a2 : b2;
      wq.w = lo ? a3 : b3;
      const bf16x8 pa = __builtin_bit_cast(bf16x8, wq);
#pragma unroll
      for (int db = 0; db < 8; ++db) {
        const int vrow = db * 16 + l15;
        const int pslot = kb2 * 4 + l4;
        bf16x8 bv = *(const bf16x8*)((const char*)Vs[cur] + vrow * 128 + ((pslot ^ (vrow & 7)) << 4));
        po[db] = __builtin_amdgcn_mfma_f32_16x16x32_bf16(pa, bv, po[db], 0, 0, 0);
      }
    }
    __syncthreads();
    cur ^= 1;
  }

  float rl[4];
#pragma unroll
  for (int r = 0; r < 4; ++r) rl[r] = 1.f / __shfl(lrow, l4 * 4 + r, 16);
#pragma unroll
  for (int db = 0; db < 8; ++db)
#pragma unroll
    for (int r = 0; r < 4; ++r) {
      const int sq = sq_base + l4 * 4 + r;
      const int d = db * 16 + l15;
      ctx[(size_t)sq * (NHEADS * HD) + h * HD + d] = f2bf(po[db][r] * rl[r]);
    }
}

extern "C" void kernel_launch(void* const* d_in, const int* in_sizes, int n_in,
                              void* d_out, int out_size, void* d_ws, size_t ws_size,
                              hipStream_t stream) {
  const float* hs = (const float*)d_in[0];
  const int* pos = (const int*)d_in[1];
  const float* Wq = (const float*)d_in[2];
  const float* Wk = (const float*)d_in[3];
  const float* Wv = (const float*)d_in[4];
  const float* Wo = (const float*)d_in[5];

  u16* ws = (u16*)d_ws;
  u16* Xb = ws;                                   // [2048][4096]
  u16* Wqt = Xb + (size_t)2048 * 4096;            // [4096][4096]
  u16* Wkt = Wqt + (size_t)4096 * 4096;           // [1024][4096]
  u16* Wvt = Wkt + (size_t)1024 * 4096;           // [1024][4096]
  u16* Wot = Wvt + (size_t)1024 * 4096;           // [4096][4096]
  u16* qb = Wot + (size_t)4096 * 4096;            // [2048][4096]
  u16* kb = qb + (size_t)2048 * 4096;             // [2048][1024]
  u16* vb = kb + (size_t)2048 * 1024;             // [2048][1024]
  u16* vtb = vb + (size_t)2048 * 1024;            // [1024][2048]
  u16* ctx = vtb + (size_t)1024 * 2048;           // [2048][4096]
  const size_t need = ((size_t)(ctx - ws) + (size_t)2048 * 4096) * 2;
  if (ws_size < need) return;

  // fused X conversion + Wq/Wk/Wv transposes
  prep_all<<<14336, 256, 0, stream>>>(hs, Xb, Wq, Wqt, Wk, Wkt, Wv, Wvt);

  // fused Q+K+V projections (192 gemm blocks, row-panel-per-XCD) + folded Wo transpose
  gemm8p32<<<256, 512, 0, stream>>>(Xb, Wqt, Wkt, Wvt, qb, kb, vb, Wo, Wot);

  // fused RoPE(q) + RoPE(k) + V transpose
  post_qkv<<<22528, 256, 0, stream>>>(qb, kb, vb, vtb, pos);

  // kv-head-per-XCD attention
  attn_fwd<<<1024, 256, 0, stream>>>(qb, kb, vtb, ctx);

  // output projection -> fp32 d_out (2 row-panels per XCD)
  gemm8p16<<<256, 512, 0, stream>>>(ctx, Wot, (float*)d_out);
}

// Round 8
// 343.500 us; speedup vs baseline: 1.1967x; 1.0019x over previous
//
#include <hip/hip_runtime.h>
#include <hip/hip_bf16.h>
#include <math.h>

#define SEQ 2048
#define NHEADS 32
#define NKVH 8
#define HD 128
#define HIDDEN 4096

typedef unsigned short u16;
typedef unsigned int u32;
typedef __attribute__((ext_vector_type(8))) __bf16 bf16x8;
typedef __attribute__((ext_vector_type(4))) float f32x4;
typedef __attribute__((ext_vector_type(16))) float f32x16;
typedef __attribute__((ext_vector_type(4))) u16 u16x4;
typedef __attribute__((ext_vector_type(4))) u32 u32x4;

__device__ __forceinline__ u16 f2bf(float f) {
  u32 u = __builtin_bit_cast(u32, f);
  u32 r = (u + 0x7fffu + ((u >> 16) & 1u)) >> 16;
  return (u16)r;
}
__device__ __forceinline__ float bf2f(u16 h) {
  return __builtin_bit_cast(float, ((u32)h) << 16);
}
__device__ __forceinline__ void gload_lds16(const void* g, void* l) {
  __builtin_amdgcn_global_load_lds(
      (const __attribute__((address_space(1))) u32*)g,
      (__attribute__((address_space(3))) u32*)l, 16, 0, 0);
}

#define BAR __builtin_amdgcn_s_barrier()
#define PRIO1 __builtin_amdgcn_s_setprio(1)
#define PRIO0 __builtin_amdgcn_s_setprio(0)
#define VMW(n) asm volatile("s_waitcnt vmcnt(" #n ")" ::: "memory")

// ---------------- fused prep: X f32->bf16 + Wq/Wk/Wv transpose f32->bf16^T ----------------
__global__ void __launch_bounds__(256) prep_all(
    const float* __restrict__ hs, u16* __restrict__ Xb,
    const float* __restrict__ Wq, u16* __restrict__ Wqt,
    const float* __restrict__ Wk, u16* __restrict__ Wkt,
    const float* __restrict__ Wv, u16* __restrict__ Wvt) {
  const int bid = blockIdx.x;
  if (bid < 8192) {  // X conversion, 4 f32/thread
    const int i = (bid * 256 + threadIdx.x) * 4;
    const float4 v = *(const float4*)(hs + i);
    u16x4 o;
    o.x = f2bf(v.x); o.y = f2bf(v.y); o.z = f2bf(v.z); o.w = f2bf(v.w);
    *(u16x4*)(Xb + i) = o;
    return;
  }
  __shared__ float tile[64][65];
  const float* src; u16* dst; int C, lc, tb;
  const int b2 = bid - 8192;
  if (b2 < 4096) { src = Wq; dst = Wqt; C = 4096; lc = 6; tb = b2; }
  else if (b2 < 5120) { src = Wk; dst = Wkt; C = 1024; lc = 4; tb = b2 - 4096; }
  else { src = Wv; dst = Wvt; C = 1024; lc = 4; tb = b2 - 5120; }
  const int r0 = (tb >> lc) * 64, c0 = (tb & ((1 << lc) - 1)) * 64;
  const int tx = threadIdx.x & 63, ty = threadIdx.x >> 6;
#pragma unroll
  for (int j = 0; j < 16; ++j)
    tile[ty + j * 4][tx] = src[(size_t)(r0 + ty + j * 4) * C + c0 + tx];
  __syncthreads();
#pragma unroll
  for (int j = 0; j < 16; ++j)
    dst[(size_t)(c0 + ty + j * 4) * 4096 + r0 + tx] = f2bf(tile[tx][ty + j * 4]);
}

// ---------------- fused post-QKV: RoPE(q)+RoPE(k) + V transpose ----------------
__global__ void __launch_bounds__(256) post_qkv(u16* __restrict__ qb, u16* __restrict__ kb,
                                                const u16* __restrict__ vb, u16* __restrict__ vtb,
                                                const int* __restrict__ pos) {
  const int bid = blockIdx.x;
  if (bid < 20480) {  // RoPE
    u16* x; int lognh; float oscale;
    int idx;
    if (bid < 16384) {
      x = qb; lognh = 5;
      oscale = 0.08838834764831845f * 1.44269504088896340f;  // 1/sqrt(128)*log2(e)
      idx = bid * 256 + threadIdx.x;
    } else {
      x = kb; lognh = 3; oscale = 1.0f;
      idx = (bid - 16384) * 256 + threadIdx.x;
    }
    const int j = idx & 63;
    const int hh = (idx >> 6) & ((1 << lognh) - 1);
    const int s = idx >> (6 + lognh);
    if (s >= SEQ) return;
    const float p = (float)pos[s];
    const float invf = __expf((float)j * -0.14391156831212787f);  // -ln(10000)/64
    const float ang = p * invf;
    const float c = cosf(ang), sn = sinf(ang);
    u16* bp = x + ((size_t)s << (7 + lognh)) + hh * 128 + j;
    const float x1 = bf2f(bp[0]), x2 = bf2f(bp[64]);
    bp[0] = f2bf((x1 * c - x2 * sn) * oscale);
    bp[64] = f2bf((x2 * c + x1 * sn) * oscale);
    return;
  }
  // V transpose: vb [2048][1024] -> vtb [1024][2048]
  __shared__ u16 tile[32][34];
  const int b2 = bid - 20480;
  const int c0 = (b2 & 31) * 32, r0 = (b2 >> 5) * 32;
  const int tx = threadIdx.x & 31, ty = threadIdx.x >> 5;
#pragma unroll
  for (int i = 0; i < 4; ++i)
    tile[ty + i * 8][tx] = vb[(size_t)(r0 + ty + i * 8) * 1024 + c0 + tx];
  __syncthreads();
#pragma unroll
  for (int i = 0; i < 4; ++i)
    vtb[(size_t)(c0 + ty + i * 8) * 2048 + r0 + tx] = tile[tx][ty + i * 8];
}

// ================= 4-superphase GEMM, 32x32x16 MFMA, BM=BN=256, BK=64 =================
// Superphase = 2 quadrants (32 MFMA) per barrier pair -> 8 barriers/iter (was 16).
// Stage timeline: S1: buf0.A0<-t+2; S2: buf0.{B0,B1,A1}<-t+2; S3: buf1.A0<-t+3;
// S0: buf1.{B0,B1,A1}<-t+1 (just-in-time, gated by end-S1 VMW).
template <int MH, int NH>
__device__ __forceinline__ void mfq32(f32x16 (&acc)[4][2], const bf16x8 (&afr)[2][4],
                                      const bf16x8 (&b)[4]) {
#pragma unroll
  for (int f = 0; f < 2; ++f)
#pragma unroll
    for (int ks = 0; ks < 4; ++ks)
      acc[MH * 2 + f][NH] = __builtin_amdgcn_mfma_f32_32x32x16_bf16(
          afr[f][ks], b[ks], acc[MH * 2 + f][NH], 0, 0, 0);
}

__global__ void __launch_bounds__(512, 2) gemm8p32(
    const u16* __restrict__ A, const u16* __restrict__ B0q, const u16* __restrict__ B1q,
    const u16* __restrict__ B2q, u16* __restrict__ C0, u16* __restrict__ C1,
    u16* __restrict__ C2, const float* __restrict__ Wsrc, u16* __restrict__ Wdst) {
  __shared__ u16 As[2][2][128 * 64];
  __shared__ u16 Bs[2][2][128 * 64];
  const int t = threadIdx.x;
  const int flat = blockIdx.x;
  const int xcd = flat & 7, idx = flat >> 3;  // 8 XCDs x 32 slots

  if (idx >= 24) {  // ---- folded Wo transpose (f32 [4096][4096] -> bf16^T), 8 blocks/XCD ----
    const int wid = xcd * 8 + (idx - 24);  // 0..63, rows [wid*64, +64)
    float* tf = (float*)&As[0][0][0];
    const int tx = t & 63, ty = t >> 6;
    const int r0 = wid * 64;
    for (int ct = 0; ct < 64; ++ct) {
      const int c0 = ct * 64;
#pragma unroll
      for (int i = 0; i < 8; ++i)
        tf[(ty + i * 8) * 65 + tx] = Wsrc[(size_t)(r0 + ty + i * 8) * 4096 + c0 + tx];
      __syncthreads();
#pragma unroll
      for (int i = 0; i < 8; ++i)
        Wdst[(size_t)(c0 + ty + i * 8) * 4096 + r0 + tx] = f2bf(tf[tx * 65 + ty + i * 8]);
      __syncthreads();
    }
    return;
  }

  const int lane = t & 63, w = t >> 6;
  const int wr = w >> 2, wc = w & 3;
  const int l31 = lane & 31, l5 = lane >> 5;

  int bxt = idx;            // 0..23: col tile
  const int byt = xcd;      // row tile per XCD
  const u16* Bp; u16* Cw; int Nn;
  if (bxt < 16) { Bp = B0q; Cw = C0; Nn = 4096; }
  else if (bxt < 20) { bxt -= 16; Bp = B1q; Cw = C1; Nn = 1024; }
  else { bxt -= 20; Bp = B2q; Cw = C2; Nn = 1024; }
  const int row0 = byt * 256, col0 = bxt * 256;

  auto stageA = [&](int buf, int half, int tile) {
#pragma unroll
    for (int g = 0; g < 2; ++g) {
      const int o = (g * 512 + t) * 16;
      const int ridx = o >> 7;
      const int slot = (o >> 4) & 7;
      const int gr = (ridx >> 6) * 128 + half * 64 + (ridx & 63);
      gload_lds16(A + (size_t)(row0 + gr) * 4096 + (tile << 6) + ((slot ^ (ridx & 7)) << 3),
                  (char*)&As[buf][half][0] + o);
    }
  };
  auto stageB = [&](int buf, int half, int tile) {
#pragma unroll
    for (int g = 0; g < 2; ++g) {
      const int o = (g * 512 + t) * 16;
      const int ridx = o >> 7;
      const int slot = (o >> 4) & 7;
      const int gn = (ridx >> 5) * 64 + half * 32 + (ridx & 31);
      gload_lds16(Bp + (size_t)(col0 + gn) * 4096 + (tile << 6) + ((slot ^ (ridx & 7)) << 3),
                  (char*)&Bs[buf][half][0] + o);
    }
  };

  bf16x8 afr[2][4], bf0[4], bf1[4];
  auto loadA32 = [&](int buf, int half) {
#pragma unroll
    for (int f = 0; f < 2; ++f)
#pragma unroll
      for (int ks = 0; ks < 4; ++ks) {
        const int idx2 = wr * 64 + f * 32 + l31;
        const int slot = ks * 2 + l5;
        afr[f][ks] = *(const bf16x8*)((const char*)&As[buf][half][0] + idx2 * 128 +
                                      ((slot ^ (idx2 & 7)) << 4));
      }
  };
  auto loadB32 = [&](int buf, int half, bf16x8 (&dst)[4]) {
#pragma unroll
    for (int ks = 0; ks < 4; ++ks) {
      const int idx2 = wc * 32 + l31;
      const int slot = ks * 2 + l5;
      dst[ks] = *(const bf16x8*)((const char*)&Bs[buf][half][0] + idx2 * 128 +
                                 ((slot ^ (idx2 & 7)) << 4));
    }
  };

  f32x16 acc[4][2];
#pragma unroll
  for (int m_ = 0; m_ < 4; ++m_)
#pragma unroll
    for (int n_ = 0; n_ < 2; ++n_)
#pragma unroll
      for (int e = 0; e < 16; ++e) acc[m_][n_][e] = 0.f;

  const int nit = (4096 >> 6) >> 1;  // 32 pairs

  // prologue: buf0 <- t0 fully (8 gl); buf1.A0 <- t1 (2 gl)
  stageA(0, 0, 0); stageB(0, 0, 0); stageB(0, 1, 0); stageA(0, 1, 0);
  stageA(1, 0, 1);
  VMW(2);  // buf0 landed; buf1.A0 in flight
  BAR;

  for (int i = 0; i < nit; ++i) {
    const int tb = 2 * i;
    const bool g2 = (i + 1 < nit);
    // S0: stage buf1.{B0,B1,A1} <- tb+1 (just-in-time); read buf0.{A0,B0,B1}
    stageB(1, 0, tb + 1); stageB(1, 1, tb + 1); stageA(1, 1, tb + 1);
    loadA32(0, 0); loadB32(0, 0, bf0); loadB32(0, 1, bf1);
    BAR; PRIO1; mfq32<0, 0>(acc, afr, bf0); mfq32<0, 1>(acc, afr, bf1); PRIO0; BAR;
    // S1: stage buf0.A0 <- tb+2; read buf0.A1; gate buf1 readiness
    if (g2) stageA(0, 0, tb + 2);
    loadA32(0, 1);
    BAR; PRIO1; mfq32<1, 1>(acc, afr, bf1); mfq32<1, 0>(acc, afr, bf0); PRIO0;
    if (g2) { VMW(2); } else { VMW(0); }
    BAR;
    // S2: stage buf0.{B0,B1,A1} <- tb+2; read buf1.{A0,B0,B1}
    if (g2) { stageB(0, 0, tb + 2); stageB(0, 1, tb + 2); stageA(0, 1, tb + 2); }
    loadA32(1, 0); loadB32(1, 0, bf0); loadB32(1, 1, bf1);
    BAR; PRIO1; mfq32<0, 0>(acc, afr, bf0); mfq32<0, 1>(acc, afr, bf1); PRIO0; BAR;
    // S3: stage buf1.A0 <- tb+3; read buf1.A1; gate buf0 readiness
    if (g2) stageA(1, 0, tb + 3);
    loadA32(1, 1);
    BAR; PRIO1; mfq32<1, 1>(acc, afr, bf1); mfq32<1, 0>(acc, afr, bf0); PRIO0;
    if (g2) { VMW(2); }
    BAR;
  }

  // epilogue: 32x32 D layout col=l&31, row=(reg&3)+8*(reg>>2)+4*(l>>5)
#pragma unroll
  for (int am = 0; am < 4; ++am)
#pragma unroll
    for (int an = 0; an < 2; ++an) {
      const int colb = col0 + wc * 64 + an * 32 + l31;
#pragma unroll
      for (int q = 0; q < 4; ++q) {
        const int rowb = row0 + wr * 128 + am * 32 + q * 8 + l5 * 4;
#pragma unroll
        for (int rr = 0; rr < 4; ++rr)
          Cw[(size_t)(rowb + rr) * Nn + colb] = f2bf(acc[am][an][q * 4 + rr]);
      }
    }
}

// ================= 8-phase GEMM, 16x16x32 MFMA, BM=128, BN=256 (Wo, f32 out) =================
template <int MH, int NH>
__device__ __forceinline__ void mfq16(f32x4 (&acc)[4][4], const bf16x8 (&af)[2][2],
                                      const bf16x8 (&b)[2][2]) {
#pragma unroll
  for (int f = 0; f < 2; ++f)
#pragma unroll
    for (int e = 0; e < 2; ++e)
#pragma unroll
      for (int ks = 0; ks < 2; ++ks)
        acc[MH * 2 + f][NH * 2 + e] = __builtin_amdgcn_mfma_f32_16x16x32_bf16(
            af[f][ks], b[e][ks], acc[MH * 2 + f][NH * 2 + e], 0, 0, 0);
}

__global__ void __launch_bounds__(512, 2) gemm8p16(
    const u16* __restrict__ A, const u16* __restrict__ B, float* __restrict__ C) {
  __shared__ u16 As[2][2][64 * 64];
  __shared__ u16 Bs[2][2][128 * 64];
  const int t = threadIdx.x;
  const int lane = t & 63, w = t >> 6;
  const int wr = w >> 2, wc = w & 3;
  const int l15 = lane & 15, l4 = lane >> 4;

  const int flat = blockIdx.x;
  const int xcd = flat & 7, idx = flat >> 3;
  const int bxt = idx & 15, byt = xcd * 2 + (idx >> 4);
  const int row0 = byt * 128, col0 = bxt * 256;

  auto stageA = [&](int buf, int half, int tile) {
    const int o = t * 16;
    const int ridx = o >> 7;
    const int slot = (o >> 4) & 7;
    const int gr = (ridx >> 5) * 64 + half * 32 + (ridx & 31);
    gload_lds16(A + (size_t)(row0 + gr) * 4096 + (tile << 6) + ((slot ^ (ridx & 7)) << 3),
                (char*)&As[buf][half][0] + o);
  };
  auto stageB = [&](int buf, int half, int tile) {
#pragma unroll
    for (int g = 0; g < 2; ++g) {
      const int o = (g * 512 + t) * 16;
      const int ridx = o >> 7;
      const int slot = (o >> 4) & 7;
      const int gn = (ridx >> 5) * 64 + half * 32 + (ridx & 31);
      gload_lds16(B + (size_t)(col0 + gn) * 4096 + (tile << 6) + ((slot ^ (ridx & 7)) << 3),
                  (char*)&Bs[buf][half][0] + o);
    }
  };

  bf16x8 af[2][2], bf0[2][2], bf1[2][2];
  auto loadA = [&](int buf, int half) {
#pragma unroll
    for (int f = 0; f < 2; ++f)
#pragma unroll
      for (int ks = 0; ks < 2; ++ks) {
        const int idx2 = wr * 32 + f * 16 + l15;
        const int slot = ks * 4 + l4;
        af[f][ks] = *(const bf16x8*)((const char*)&As[buf][half][0] + idx2 * 128 +
                                     ((slot ^ (idx2 & 7)) << 4));
      }
  };
  auto loadB = [&](int buf, int half, bf16x8 (&dst)[2][2]) {
#pragma unroll
    for (int e = 0; e < 2; ++e)
#pragma unroll
      for (int ks = 0; ks < 2; ++ks) {
        const int idx2 = wc * 32 + e * 16 + l15;
        const int slot = ks * 4 + l4;
        dst[e][ks] = *(const bf16x8*)((const char*)&Bs[buf][half][0] + idx2 * 128 +
                                      ((slot ^ (idx2 & 7)) << 4));
      }
  };

  f32x4 acc[4][4];
#pragma unroll
  for (int m_ = 0; m_ < 4; ++m_)
#pragma unroll
    for (int n_ = 0; n_ < 4; ++n_) acc[m_][n_] = f32x4{0.f, 0.f, 0.f, 0.f};

  const int nit = (4096 >> 6) >> 1;

  stageA(0, 0, 0); stageB(0, 0, 0); stageB(0, 1, 0); stageA(0, 1, 0);
  stageA(1, 0, 1); stageB(1, 0, 1); stageB(1, 1, 1); stageA(1, 1, 1);
  VMW(6);
  BAR;

  for (int i = 0; i < nit; ++i) {
    const int tb = 2 * i;
    const bool g2 = (i + 1 < nit);
    // p0: reads A00,B00
    loadA(0, 0); loadB(0, 0, bf0);
    BAR; PRIO1; mfq16<0, 0>(acc, af, bf0); PRIO0; BAR;
    // p1: reads B01; restage A00,B00
    loadB(0, 1, bf1);
    if (g2) { stageA(0, 0, tb + 2); stageB(0, 0, tb + 2); }
    BAR; PRIO1; mfq16<0, 1>(acc, af, bf1); PRIO0; BAR;
    // p2: reads A01; restage B01
    loadA(0, 1);
    if (g2) stageB(0, 1, tb + 2);
    BAR; PRIO1; mfq16<1, 1>(acc, af, bf1); PRIO0; BAR;
    // p3: reuse B0; restage A01; counted wait
    if (g2) stageA(0, 1, tb + 2);
    BAR; PRIO1; mfq16<1, 0>(acc, af, bf0); PRIO0;
    if (g2) { VMW(6); } else { VMW(0); }
    BAR;
    // p4: reads A10,B10
    loadA(1, 0); loadB(1, 0, bf0);
    BAR; PRIO1; mfq16<0, 0>(acc, af, bf0); PRIO0; BAR;
    // p5: reads B11; restage A10,B10
    loadB(1, 1, bf1);
    if (g2) { stageA(1, 0, tb + 3); stageB(1, 0, tb + 3); }
    BAR; PRIO1; mfq16<0, 1>(acc, af, bf1); PRIO0; BAR;
    // p6: reads A11; restage B11
    loadA(1, 1);
    if (g2) stageB(1, 1, tb + 3);
    BAR; PRIO1; mfq16<1, 1>(acc, af, bf1); PRIO0; BAR;
    // p7: reuse B0; restage A11; counted wait
    if (g2) stageA(1, 1, tb + 3);
    BAR; PRIO1; mfq16<1, 0>(acc, af, bf0); PRIO0;
    if (g2) { VMW(6); } else { }
    BAR;
  }

#pragma unroll
  for (int am = 0; am < 4; ++am) {
    const int rowb = row0 + wr * 64 + (am >> 1) * 32 + (am & 1) * 16 + l4 * 4;
#pragma unroll
    for (int an = 0; an < 4; ++an) {
      const int colb = col0 + wc * 64 + (an >> 1) * 32 + (an & 1) * 16 + l15;
#pragma unroll
      for (int r = 0; r < 4; ++r)
        C[(size_t)(rowb + r) * 4096 + colb] = acc[am][an][r];
    }
  }
}

// ---------------- attention staging: K tile [64][128] + V^T tile [128][64], swizzled ----------------
__device__ __forceinline__ void stage_kv(const u16* __restrict__ k, const u16* __restrict__ vt,
                                         const int kvh, const int kv0, u16* KsB, u16* VsB,
                                         const int t) {
#pragma unroll
  for (int i = 0; i < 4; ++i) {
    const int o = (i * 256 + t) * 16;
    const int row = o >> 8;
    const int slot = (o >> 4) & 15;
    gload_lds16(k + (size_t)(kv0 + row) * (NKVH * HD) + kvh * HD + ((slot ^ (row & 7)) << 3),
                (char*)KsB + o);
  }
#pragma unroll
  for (int i = 0; i < 4; ++i) {
    const int o = (i * 256 + t) * 16;
    const int row = o >> 7;
    const int slot = (o >> 4) & 7;
    gload_lds16(vt + (size_t)(kvh * HD + row) * SEQ + kv0 + ((slot ^ (row & 7)) << 3),
                (char*)VsB + o);
  }
}

// ---------------- causal GQA flash attention, swapped-QK in-register softmax ----------------
__global__ void __launch_bounds__(256) attn_fwd(const u16* __restrict__ q, const u16* __restrict__ k,
                                                const u16* __restrict__ vt, u16* __restrict__ ctx) {
  __shared__ u16 Ks[2][64 * 128];
  __shared__ u16 Vs[2][128 * 64];
  const int t = threadIdx.x, lane = t & 63, w = t >> 6;
  const int bid = blockIdx.x;
  const int xcd = bid & 7, bi = bid >> 3;
  const int h = xcd * 4 + (bi & 3);
  const int qb = 31 - (bi >> 2);
  const int kvh = xcd;
  const int q0 = qb * 64;
  const int sq_base = q0 + w * 16;
  const int l15 = lane & 15, l4 = lane >> 4;
  const int sq_abs = sq_base + l15;

  bf16x8 qf[4];
  {
    const u16* qp = q + (size_t)sq_abs * (NHEADS * HD) + h * HD + l4 * 8;
#pragma unroll
    for (int kb = 0; kb < 4; ++kb) qf[kb] = *(const bf16x8*)(qp + kb * 32);
  }
  f32x4 po[8];
#pragma unroll
  for (int i = 0; i < 8; ++i) po[i] = f32x4{0.f, 0.f, 0.f, 0.f};
  float mrow = -1e30f;
  float lrow = 0.f;

  const int nb = qb + 1;
  stage_kv(k, vt, kvh, 0, Ks[0], Vs[0], t);
  __syncthreads();
  int cur = 0;

  for (int b = 0; b < nb; ++b) {
    if (b + 1 < nb) stage_kv(k, vt, kvh, (b + 1) * 64, Ks[cur ^ 1], Vs[cur ^ 1], t);

    f32x4 st[4];
#pragma unroll
    for (int c = 0; c < 4; ++c) st[c] = f32x4{0.f, 0.f, 0.f, 0.f};
#pragma unroll
    for (int c = 0; c < 4; ++c) {
      const int row = c * 16 + l15;
#pragma unroll
      for (int kb = 0; kb < 4; ++kb) {
        const int slot = kb * 4 + l4;
        bf16x8 bk = *(const bf16x8*)((const char*)Ks[cur] + row * 256 + ((slot ^ (row & 7)) << 4));
        st[c] = __builtin_amdgcn_mfma_f32_16x16x32_bf16(bk, qf[kb], st[c], 0, 0, 0);
      }
    }

    if (b == nb - 1) {
#pragma unroll
      for (int c = 0; c < 4; ++c)
#pragma unroll
        for (int r = 0; r < 4; ++r) {
          const int sk = b * 64 + c * 16 + l4 * 4 + r;
          if (sk > sq_abs) st[c][r] = -1e30f;
        }
    }

    float rmax = -3e38f;
#pragma unroll
    for (int c = 0; c < 4; ++c)
      rmax = fmaxf(rmax, fmaxf(fmaxf(st[c][0], st[c][1]), fmaxf(st[c][2], st[c][3])));
    rmax = fmaxf(rmax, __shfl_xor(rmax, 16, 64));
    rmax = fmaxf(rmax, __shfl_xor(rmax, 32, 64));

    const bool skip = __all(rmax <= mrow + 8.f);
    const float mnew = skip ? mrow : fmaxf(mrow, rmax);

    float rs = 0.f;
#pragma unroll
    for (int c = 0; c < 4; ++c) {
      const float e0 = exp2f(st[c][0] - mnew), e1 = exp2f(st[c][1] - mnew);
      const float e2 = exp2f(st[c][2] - mnew), e3 = exp2f(st[c][3] - mnew);
      st[c][0] = e0; st[c][1] = e1; st[c][2] = e2; st[c][3] = e3;
      rs += (e0 + e1) + (e2 + e3);
    }
    rs += __shfl_xor(rs, 16, 64);
    rs += __shfl_xor(rs, 32, 64);

    if (!skip) {
      const float alpha = exp2f(mrow - mnew);
      mrow = mnew;
      lrow = lrow * alpha + rs;
      float av[4];
#pragma unroll
      for (int r = 0; r < 4; ++r) av[r] = __shfl(alpha, l4 * 4 + r, 16);
#pragma unroll
      for (int db = 0; db < 8; ++db)
#pragma unroll
        for (int r = 0; r < 4; ++r) po[db][r] *= av[r];
    } else {
      lrow += rs;
    }

    u32 pk[4][2];
#pragma unroll
    for (int c = 0; c < 4; ++c) {
      pk[c][0] = (u32)f2bf(st[c][0]) | ((u32)f2bf(st[c][1]) << 16);
      pk[c][1] = (u32)f2bf(st[c][2]) | ((u32)f2bf(st[c][3]) << 16);
    }
    const int src01 = l15 + ((lane & 16) << 1);
    const int src23 = src01 + 16;
    const bool lo = (lane & 32) == 0;
#pragma unroll
    for (int kb2 = 0; kb2 < 2; ++kb2) {
      const int c0 = kb2 * 2, c1 = c0 + 1;
      const u32 a0 = (u32)__shfl((int)pk[c0][0], src01, 64);
      const u32 a1 = (u32)__shfl((int)pk[c0][1], src01, 64);
      const u32 a2 = (u32)__shfl((int)pk[c0][0], src23, 64);
      const u32 a3 = (u32)__shfl((int)pk[c0][1], src23, 64);
      const u32 b0 = (u32)__shfl((int)pk[c1][0], src01, 64);
      const u32 b1 = (u32)__shfl((int)pk[c1][1], src01, 64);
      const u32 b2 = (u32)__shfl((int)pk[c1][0], src23, 64);
      const u32 b3 = (u32)__shfl((int)pk[c1][1], src23, 64);
      u32x4 wq;
      wq.x = lo ? a0 : b0;
      wq.y = lo ? a1 : b1;
      wq.z = lo ? a2 : b2;
      wq.w = lo ? a3 : b3;
      const bf16x8 pa = __builtin_bit_cast(bf16x8, wq);
#pragma unroll
      for (int db = 0; db < 8; ++db) {
        const int vrow = db * 16 + l15;
        const int pslot = kb2 * 4 + l4;
        bf16x8 bv = *(const bf16x8*)((const char*)Vs[cur] + vrow * 128 + ((pslot ^ (vrow & 7)) << 4));
        po[db] = __builtin_amdgcn_mfma_f32_16x16x32_bf16(pa, bv, po[db], 0, 0, 0);
      }
    }
    __syncthreads();
    cur ^= 1;
  }

  float rl[4];
#pragma unroll
  for (int r = 0; r < 4; ++r) rl[r] = 1.f / __shfl(lrow, l4 * 4 + r, 16);
#pragma unroll
  for (int db = 0; db < 8; ++db)
#pragma unroll
    for (int r = 0; r < 4; ++r) {
      const int sq = sq_base + l4 * 4 + r;
      const int d = db * 16 + l15;
      ctx[(size_t)sq * (NHEADS * HD) + h * HD + d] = f2bf(po[db][r] * rl[r]);
    }
}

extern "C" void kernel_launch(void* const* d_in, const int* in_sizes, int n_in,
                              void* d_out, int out_size, void* d_ws, size_t ws_size,
                              hipStream_t stream) {
  const float* hs = (const float*)d_in[0];
  const int* pos = (const int*)d_in[1];
  const float* Wq = (const float*)d_in[2];
  const float* Wk = (const float*)d_in[3];
  const float* Wv = (const float*)d_in[4];
  const float* Wo = (const float*)d_in[5];

  u16* ws = (u16*)d_ws;
  u16* Xb = ws;                                   // [2048][4096]
  u16* Wqt = Xb + (size_t)2048 * 4096;            // [4096][4096]
  u16* Wkt = Wqt + (size_t)4096 * 4096;           // [1024][4096]
  u16* Wvt = Wkt + (size_t)1024 * 4096;           // [1024][4096]
  u16* Wot = Wvt + (size_t)1024 * 4096;           // [4096][4096]
  u16* qb = Wot + (size_t)4096 * 4096;            // [2048][4096]
  u16* kb = qb + (size_t)2048 * 4096;             // [2048][1024]
  u16* vb = kb + (size_t)2048 * 1024;             // [2048][1024]
  u16* vtb = vb + (size_t)2048 * 1024;            // [1024][2048]
  u16* ctx = vtb + (size_t)1024 * 2048;           // [2048][4096]
  const size_t need = ((size_t)(ctx - ws) + (size_t)2048 * 4096) * 2;
  if (ws_size < need) return;

  // fused X conversion + Wq/Wk/Wv transposes
  prep_all<<<14336, 256, 0, stream>>>(hs, Xb, Wq, Wqt, Wk, Wkt, Wv, Wvt);

  // fused Q+K+V projections (192 gemm blocks, 4-superphase) + folded Wo transpose
  gemm8p32<<<256, 512, 0, stream>>>(Xb, Wqt, Wkt, Wvt, qb, kb, vb, Wo, Wot);

  // fused RoPE(q) + RoPE(k) + V transpose
  post_qkv<<<22528, 256, 0, stream>>>(qb, kb, vb, vtb, pos);

  // kv-head-per-XCD attention
  attn_fwd<<<1024, 256, 0, stream>>>(qb, kb, vtb, ctx);

  // output projection -> fp32 d_out
  gemm8p16<<<256, 512, 0, stream>>>(ctx, Wot, (float*)d_out);
}

// Round 9
// 338.379 us; speedup vs baseline: 1.2148x; 1.0151x over previous
//
#include <hip/hip_runtime.h>
#include <hip/hip_bf16.h>
#include <math.h>

#define SEQ 2048
#define NHEADS 32
#define NKVH 8
#define HD 128
#define HIDDEN 4096

typedef unsigned short u16;
typedef unsigned int u32;
typedef __attribute__((ext_vector_type(8))) __bf16 bf16x8;
typedef __attribute__((ext_vector_type(4))) float f32x4;
typedef __attribute__((ext_vector_type(16))) float f32x16;
typedef __attribute__((ext_vector_type(4))) u16 u16x4;
typedef __attribute__((ext_vector_type(4))) u32 u32x4;

__device__ __forceinline__ u16 f2bf(float f) {
  u32 u = __builtin_bit_cast(u32, f);
  u32 r = (u + 0x7fffu + ((u >> 16) & 1u)) >> 16;
  return (u16)r;
}
__device__ __forceinline__ float bf2f(u16 h) {
  return __builtin_bit_cast(float, ((u32)h) << 16);
}
__device__ __forceinline__ void gload_lds16(const void* g, void* l) {
  __builtin_amdgcn_global_load_lds(
      (const __attribute__((address_space(1))) u32*)g,
      (__attribute__((address_space(3))) u32*)l, 16, 0, 0);
}

#define BAR __builtin_amdgcn_s_barrier()
#define PRIO1 __builtin_amdgcn_s_setprio(1)
#define PRIO0 __builtin_amdgcn_s_setprio(0)
#define VMW(n) asm volatile("s_waitcnt vmcnt(" #n ")" ::: "memory")

// ---------------- fused prep: X f32->bf16 + Wq/Wk/Wv transpose f32->bf16^T ----------------
__global__ void __launch_bounds__(256) prep_all(
    const float* __restrict__ hs, u16* __restrict__ Xb,
    const float* __restrict__ Wq, u16* __restrict__ Wqt,
    const float* __restrict__ Wk, u16* __restrict__ Wkt,
    const float* __restrict__ Wv, u16* __restrict__ Wvt) {
  const int bid = blockIdx.x;
  if (bid < 8192) {  // X conversion, 4 f32/thread
    const int i = (bid * 256 + threadIdx.x) * 4;
    const float4 v = *(const float4*)(hs + i);
    u16x4 o;
    o.x = f2bf(v.x); o.y = f2bf(v.y); o.z = f2bf(v.z); o.w = f2bf(v.w);
    *(u16x4*)(Xb + i) = o;
    return;
  }
  __shared__ float tile[64][65];
  const float* src; u16* dst; int C, lc, tb;
  const int b2 = bid - 8192;
  if (b2 < 4096) { src = Wq; dst = Wqt; C = 4096; lc = 6; tb = b2; }
  else if (b2 < 5120) { src = Wk; dst = Wkt; C = 1024; lc = 4; tb = b2 - 4096; }
  else { src = Wv; dst = Wvt; C = 1024; lc = 4; tb = b2 - 5120; }
  const int r0 = (tb >> lc) * 64, c0 = (tb & ((1 << lc) - 1)) * 64;
  const int tx = threadIdx.x & 63, ty = threadIdx.x >> 6;
#pragma unroll
  for (int j = 0; j < 16; ++j)
    tile[ty + j * 4][tx] = src[(size_t)(r0 + ty + j * 4) * C + c0 + tx];
  __syncthreads();
#pragma unroll
  for (int j = 0; j < 16; ++j)
    dst[(size_t)(c0 + ty + j * 4) * 4096 + r0 + tx] = f2bf(tile[tx][ty + j * 4]);
}

// ---------------- fused post-QKV: RoPE(q)+RoPE(k) + V transpose ----------------
__global__ void __launch_bounds__(256) post_qkv(u16* __restrict__ qb, u16* __restrict__ kb,
                                                const u16* __restrict__ vb, u16* __restrict__ vtb,
                                                const int* __restrict__ pos) {
  const int bid = blockIdx.x;
  if (bid < 20480) {  // RoPE
    u16* x; int lognh; float oscale;
    int idx;
    if (bid < 16384) {
      x = qb; lognh = 5;
      oscale = 0.08838834764831845f * 1.44269504088896340f;  // 1/sqrt(128)*log2(e)
      idx = bid * 256 + threadIdx.x;
    } else {
      x = kb; lognh = 3; oscale = 1.0f;
      idx = (bid - 16384) * 256 + threadIdx.x;
    }
    const int j = idx & 63;
    const int hh = (idx >> 6) & ((1 << lognh) - 1);
    const int s = idx >> (6 + lognh);
    if (s >= SEQ) return;
    const float p = (float)pos[s];
    const float invf = __expf((float)j * -0.14391156831212787f);  // -ln(10000)/64
    const float ang = p * invf;
    const float c = cosf(ang), sn = sinf(ang);
    u16* bp = x + ((size_t)s << (7 + lognh)) + hh * 128 + j;
    const float x1 = bf2f(bp[0]), x2 = bf2f(bp[64]);
    bp[0] = f2bf((x1 * c - x2 * sn) * oscale);
    bp[64] = f2bf((x2 * c + x1 * sn) * oscale);
    return;
  }
  // V transpose: vb [2048][1024] -> vtb [1024][2048]
  __shared__ u16 tile[32][34];
  const int b2 = bid - 20480;
  const int c0 = (b2 & 31) * 32, r0 = (b2 >> 5) * 32;
  const int tx = threadIdx.x & 31, ty = threadIdx.x >> 5;
#pragma unroll
  for (int i = 0; i < 4; ++i)
    tile[ty + i * 8][tx] = vb[(size_t)(r0 + ty + i * 8) * 1024 + c0 + tx];
  __syncthreads();
#pragma unroll
  for (int i = 0; i < 4; ++i)
    vtb[(size_t)(c0 + ty + i * 8) * 2048 + r0 + tx] = tile[tx][ty + i * 8];
}

// ================= 8-phase GEMM, 32x32x16 MFMA, BM=BN=256, BK=64 (r7-best schedule) =================
template <int MH, int NH>
__device__ __forceinline__ void mfq32(f32x16 (&acc)[4][2], const bf16x8 (&afr)[2][4],
                                      const bf16x8 (&b)[4]) {
#pragma unroll
  for (int f = 0; f < 2; ++f)
#pragma unroll
    for (int ks = 0; ks < 4; ++ks)
      acc[MH * 2 + f][NH] = __builtin_amdgcn_mfma_f32_32x32x16_bf16(
          afr[f][ks], b[ks], acc[MH * 2 + f][NH], 0, 0, 0);
}

__global__ void __launch_bounds__(512, 2) gemm8p32(
    const u16* __restrict__ A, const u16* __restrict__ B0q, const u16* __restrict__ B1q,
    const u16* __restrict__ B2q, u16* __restrict__ C0, u16* __restrict__ C1,
    u16* __restrict__ C2, const float* __restrict__ Wsrc, u16* __restrict__ Wdst) {
  __shared__ u16 As[2][2][128 * 64];
  __shared__ u16 Bs[2][2][128 * 64];
  const int t = threadIdx.x;
  const int flat = blockIdx.x;
  const int xcd = flat & 7, idx = flat >> 3;  // 8 XCDs x 32 slots

  if (idx >= 24) {  // ---- folded Wo transpose (f32 [4096][4096] -> bf16^T), 8 blocks/XCD ----
    const int wid = xcd * 8 + (idx - 24);  // 0..63, rows [wid*64, +64)
    float* tf = (float*)&As[0][0][0];
    const int tx = t & 63, ty = t >> 6;
    const int r0 = wid * 64;
    for (int ct = 0; ct < 64; ++ct) {
      const int c0 = ct * 64;
#pragma unroll
      for (int i = 0; i < 8; ++i)
        tf[(ty + i * 8) * 65 + tx] = Wsrc[(size_t)(r0 + ty + i * 8) * 4096 + c0 + tx];
      __syncthreads();
#pragma unroll
      for (int i = 0; i < 8; ++i)
        Wdst[(size_t)(c0 + ty + i * 8) * 4096 + r0 + tx] = f2bf(tf[tx * 65 + ty + i * 8]);
      __syncthreads();
    }
    return;
  }

  const int lane = t & 63, w = t >> 6;
  const int wr = w >> 2, wc = w & 3;
  const int l31 = lane & 31, l5 = lane >> 5;

  int bxt = idx;            // 0..23: col tile (B-panel streams via LLC)
  const int byt = xcd;      // row tile: A panel L2-resident per XCD
  const u16* Bp; u16* Cw; int Nn;
  if (bxt < 16) { Bp = B0q; Cw = C0; Nn = 4096; }
  else if (bxt < 20) { bxt -= 16; Bp = B1q; Cw = C1; Nn = 1024; }
  else { bxt -= 20; Bp = B2q; Cw = C2; Nn = 1024; }
  const int row0 = byt * 256, col0 = bxt * 256;

  auto stageA = [&](int buf, int half, int tile) {
#pragma unroll
    for (int g = 0; g < 2; ++g) {
      const int o = (g * 512 + t) * 16;
      const int ridx = o >> 7;
      const int slot = (o >> 4) & 7;
      const int gr = (ridx >> 6) * 128 + half * 64 + (ridx & 63);
      gload_lds16(A + (size_t)(row0 + gr) * 4096 + (tile << 6) + ((slot ^ (ridx & 7)) << 3),
                  (char*)&As[buf][half][0] + o);
    }
  };
  auto stageB = [&](int buf, int half, int tile) {
#pragma unroll
    for (int g = 0; g < 2; ++g) {
      const int o = (g * 512 + t) * 16;
      const int ridx = o >> 7;
      const int slot = (o >> 4) & 7;
      const int gn = (ridx >> 5) * 64 + half * 32 + (ridx & 31);
      gload_lds16(Bp + (size_t)(col0 + gn) * 4096 + (tile << 6) + ((slot ^ (ridx & 7)) << 3),
                  (char*)&Bs[buf][half][0] + o);
    }
  };

  bf16x8 afr[2][4], bf0[4], bf1[4];
  auto loadA32 = [&](int buf, int half) {
#pragma unroll
    for (int f = 0; f < 2; ++f)
#pragma unroll
      for (int ks = 0; ks < 4; ++ks) {
        const int idx2 = wr * 64 + f * 32 + l31;
        const int slot = ks * 2 + l5;
        afr[f][ks] = *(const bf16x8*)((const char*)&As[buf][half][0] + idx2 * 128 +
                                      ((slot ^ (idx2 & 7)) << 4));
      }
  };
  auto loadB32 = [&](int buf, int half, bf16x8 (&dst)[4]) {
#pragma unroll
    for (int ks = 0; ks < 4; ++ks) {
      const int idx2 = wc * 32 + l31;
      const int slot = ks * 2 + l5;
      dst[ks] = *(const bf16x8*)((const char*)&Bs[buf][half][0] + idx2 * 128 +
                                 ((slot ^ (idx2 & 7)) << 4));
    }
  };

  f32x16 acc[4][2];
#pragma unroll
  for (int m_ = 0; m_ < 4; ++m_)
#pragma unroll
    for (int n_ = 0; n_ < 2; ++n_)
#pragma unroll
      for (int e = 0; e < 16; ++e) acc[m_][n_][e] = 0.f;

  const int nit = (4096 >> 6) >> 1;  // 32 pairs

  // prologue: stage tiles 0 and 1 fully; drain tile0
  stageA(0, 0, 0); stageB(0, 0, 0); stageB(0, 1, 0); stageA(0, 1, 0);
  stageA(1, 0, 1); stageB(1, 0, 1); stageB(1, 1, 1); stageA(1, 1, 1);
  VMW(8);
  BAR;

  for (int i = 0; i < nit; ++i) {
    const int tb = 2 * i;
    const bool g2 = (i + 1 < nit);
    // p0: reads A00,B00 (tile tb)
    loadA32(0, 0); loadB32(0, 0, bf0);
    BAR; PRIO1; mfq32<0, 0>(acc, afr, bf0); PRIO0; BAR;
    // p1: reads B01; restage A00,B00 <- tb+2
    loadB32(0, 1, bf1);
    if (g2) { stageA(0, 0, tb + 2); stageB(0, 0, tb + 2); }
    BAR; PRIO1; mfq32<0, 1>(acc, afr, bf1); PRIO0; BAR;
    // p2: reads A01; restage B01 <- tb+2
    loadA32(0, 1);
    if (g2) stageB(0, 1, tb + 2);
    BAR; PRIO1; mfq32<1, 1>(acc, afr, bf1); PRIO0; BAR;
    // p3: B-half0 reused; restage A01 <- tb+2; counted wait
    if (g2) stageA(0, 1, tb + 2);
    BAR; PRIO1; mfq32<1, 0>(acc, afr, bf0); PRIO0;
    if (g2) { VMW(8); } else { VMW(0); }
    BAR;
    // p4: reads A10,B10 (tile tb+1)
    loadA32(1, 0); loadB32(1, 0, bf0);
    BAR; PRIO1; mfq32<0, 0>(acc, afr, bf0); PRIO0; BAR;
    // p5: reads B11; restage A10,B10 <- tb+3
    loadB32(1, 1, bf1);
    if (g2) { stageA(1, 0, tb + 3); stageB(1, 0, tb + 3); }
    BAR; PRIO1; mfq32<0, 1>(acc, afr, bf1); PRIO0; BAR;
    // p6: reads A11; restage B11 <- tb+3
    loadA32(1, 1);
    if (g2) stageB(1, 1, tb + 3);
    BAR; PRIO1; mfq32<1, 1>(acc, afr, bf1); PRIO0; BAR;
    // p7: B-half0 reused; restage A11 <- tb+3; counted wait
    if (g2) stageA(1, 1, tb + 3);
    BAR; PRIO1; mfq32<1, 0>(acc, afr, bf0); PRIO0;
    if (g2) { VMW(8); }
    BAR;
  }

  // epilogue: 32x32 D layout col=l&31, row=(reg&3)+8*(reg>>2)+4*(l>>5)
#pragma unroll
  for (int am = 0; am < 4; ++am)
#pragma unroll
    for (int an = 0; an < 2; ++an) {
      const int colb = col0 + wc * 64 + an * 32 + l31;
#pragma unroll
      for (int q = 0; q < 4; ++q) {
        const int rowb = row0 + wr * 128 + am * 32 + q * 8 + l5 * 4;
#pragma unroll
        for (int rr = 0; rr < 4; ++rr)
          Cw[(size_t)(rowb + rr) * Nn + colb] = f2bf(acc[am][an][q * 4 + rr]);
      }
    }
}

// ================= 8-phase GEMM, 16x16x32 MFMA, BM=128, BN=256 (Wo, f32 out) =================
template <int MH, int NH>
__device__ __forceinline__ void mfq16(f32x4 (&acc)[4][4], const bf16x8 (&af)[2][2],
                                      const bf16x8 (&b)[2][2]) {
#pragma unroll
  for (int f = 0; f < 2; ++f)
#pragma unroll
    for (int e = 0; e < 2; ++e)
#pragma unroll
      for (int ks = 0; ks < 2; ++ks)
        acc[MH * 2 + f][NH * 2 + e] = __builtin_amdgcn_mfma_f32_16x16x32_bf16(
            af[f][ks], b[e][ks], acc[MH * 2 + f][NH * 2 + e], 0, 0, 0);
}

__global__ void __launch_bounds__(512, 2) gemm8p16(
    const u16* __restrict__ A, const u16* __restrict__ B, float* __restrict__ C) {
  __shared__ u16 As[2][2][64 * 64];
  __shared__ u16 Bs[2][2][128 * 64];
  const int t = threadIdx.x;
  const int lane = t & 63, w = t >> 6;
  const int wr = w >> 2, wc = w & 3;
  const int l15 = lane & 15, l4 = lane >> 4;

  const int flat = blockIdx.x;
  const int xcd = flat & 7, idx = flat >> 3;
  const int bxt = idx & 15, byt = xcd * 2 + (idx >> 4);
  const int row0 = byt * 128, col0 = bxt * 256;

  auto stageA = [&](int buf, int half, int tile) {
    const int o = t * 16;
    const int ridx = o >> 7;
    const int slot = (o >> 4) & 7;
    const int gr = (ridx >> 5) * 64 + half * 32 + (ridx & 31);
    gload_lds16(A + (size_t)(row0 + gr) * 4096 + (tile << 6) + ((slot ^ (ridx & 7)) << 3),
                (char*)&As[buf][half][0] + o);
  };
  auto stageB = [&](int buf, int half, int tile) {
#pragma unroll
    for (int g = 0; g < 2; ++g) {
      const int o = (g * 512 + t) * 16;
      const int ridx = o >> 7;
      const int slot = (o >> 4) & 7;
      const int gn = (ridx >> 5) * 64 + half * 32 + (ridx & 31);
      gload_lds16(B + (size_t)(col0 + gn) * 4096 + (tile << 6) + ((slot ^ (ridx & 7)) << 3),
                  (char*)&Bs[buf][half][0] + o);
    }
  };

  bf16x8 af[2][2], bf0[2][2], bf1[2][2];
  auto loadA = [&](int buf, int half) {
#pragma unroll
    for (int f = 0; f < 2; ++f)
#pragma unroll
      for (int ks = 0; ks < 2; ++ks) {
        const int idx2 = wr * 32 + f * 16 + l15;
        const int slot = ks * 4 + l4;
        af[f][ks] = *(const bf16x8*)((const char*)&As[buf][half][0] + idx2 * 128 +
                                     ((slot ^ (idx2 & 7)) << 4));
      }
  };
  auto loadB = [&](int buf, int half, bf16x8 (&dst)[2][2]) {
#pragma unroll
    for (int e = 0; e < 2; ++e)
#pragma unroll
      for (int ks = 0; ks < 2; ++ks) {
        const int idx2 = wc * 32 + e * 16 + l15;
        const int slot = ks * 4 + l4;
        dst[e][ks] = *(const bf16x8*)((const char*)&Bs[buf][half][0] + idx2 * 128 +
                                      ((slot ^ (idx2 & 7)) << 4));
      }
  };

  f32x4 acc[4][4];
#pragma unroll
  for (int m_ = 0; m_ < 4; ++m_)
#pragma unroll
    for (int n_ = 0; n_ < 4; ++n_) acc[m_][n_] = f32x4{0.f, 0.f, 0.f, 0.f};

  const int nit = (4096 >> 6) >> 1;

  stageA(0, 0, 0); stageB(0, 0, 0); stageB(0, 1, 0); stageA(0, 1, 0);
  stageA(1, 0, 1); stageB(1, 0, 1); stageB(1, 1, 1); stageA(1, 1, 1);
  VMW(6);
  BAR;

  for (int i = 0; i < nit; ++i) {
    const int tb = 2 * i;
    const bool g2 = (i + 1 < nit);
    loadA(0, 0); loadB(0, 0, bf0);
    BAR; PRIO1; mfq16<0, 0>(acc, af, bf0); PRIO0; BAR;
    loadB(0, 1, bf1);
    if (g2) { stageA(0, 0, tb + 2); stageB(0, 0, tb + 2); }
    BAR; PRIO1; mfq16<0, 1>(acc, af, bf1); PRIO0; BAR;
    loadA(0, 1);
    if (g2) stageB(0, 1, tb + 2);
    BAR; PRIO1; mfq16<1, 1>(acc, af, bf1); PRIO0; BAR;
    if (g2) stageA(0, 1, tb + 2);
    BAR; PRIO1; mfq16<1, 0>(acc, af, bf0); PRIO0;
    if (g2) { VMW(6); } else { VMW(0); }
    BAR;
    loadA(1, 0); loadB(1, 0, bf0);
    BAR; PRIO1; mfq16<0, 0>(acc, af, bf0); PRIO0; BAR;
    loadB(1, 1, bf1);
    if (g2) { stageA(1, 0, tb + 3); stageB(1, 0, tb + 3); }
    BAR; PRIO1; mfq16<0, 1>(acc, af, bf1); PRIO0; BAR;
    loadA(1, 1);
    if (g2) stageB(1, 1, tb + 3);
    BAR; PRIO1; mfq16<1, 1>(acc, af, bf1); PRIO0; BAR;
    if (g2) stageA(1, 1, tb + 3);
    BAR; PRIO1; mfq16<1, 0>(acc, af, bf0); PRIO0;
    if (g2) { VMW(6); }
    BAR;
  }

#pragma unroll
  for (int am = 0; am < 4; ++am) {
    const int rowb = row0 + wr * 64 + (am >> 1) * 32 + (am & 1) * 16 + l4 * 4;
#pragma unroll
    for (int an = 0; an < 4; ++an) {
      const int colb = col0 + wc * 64 + (an >> 1) * 32 + (an & 1) * 16 + l15;
#pragma unroll
      for (int r = 0; r < 4; ++r)
        C[(size_t)(rowb + r) * 4096 + colb] = acc[am][an][r];
    }
  }
}

// ---------------- attention staging (512 threads): K [64][128] + V^T [128][64], swizzled ----------------
__device__ __forceinline__ void stage_kv512(const u16* __restrict__ k, const u16* __restrict__ vt,
                                            const int kvh, const int kv0, u16* KsB, u16* VsB,
                                            const int t) {
#pragma unroll
  for (int i = 0; i < 2; ++i) {
    const int o = (i * 512 + t) * 16;
    const int row = o >> 8;
    const int slot = (o >> 4) & 15;
    gload_lds16(k + (size_t)(kv0 + row) * (NKVH * HD) + kvh * HD + ((slot ^ (row & 7)) << 3),
                (char*)KsB + o);
  }
#pragma unroll
  for (int i = 0; i < 2; ++i) {
    const int o = (i * 512 + t) * 16;
    const int row = o >> 7;
    const int slot = (o >> 4) & 7;
    gload_lds16(vt + (size_t)(kvh * HD + row) * SEQ + kv0 + ((slot ^ (row & 7)) << 3),
                (char*)VsB + o);
  }
}

// ---------------- causal GQA flash attention: QBLK=128, 8 waves, swapped-QK in-reg softmax ----------------
// grid 512 blocks (64/XCD, kvh = xcd, 2 resident/CU). Per block: one head, 128 q-rows.
__global__ void __launch_bounds__(512) attn_fwd(const u16* __restrict__ q, const u16* __restrict__ k,
                                                const u16* __restrict__ vt, u16* __restrict__ ctx) {
  __shared__ u16 Ks[2][64 * 128];
  __shared__ u16 Vs[2][128 * 64];
  const int t = threadIdx.x, lane = t & 63, w = t >> 6;  // w 0..7
  const int bid = blockIdx.x;
  const int xcd = bid & 7, bi = bid >> 3;  // 64 blocks per XCD
  const int h = xcd * 4 + (bi & 3);        // kvh = xcd
  const int qbb = 15 - (bi >> 2);          // 16 q-superblocks of 128 rows; long first
  const int kvh = xcd;
  const int q0 = qbb * 128;
  const int sq_base = q0 + w * 16;
  const int l15 = lane & 15, l4 = lane >> 4;
  const int sq_abs = sq_base + l15;
  const int bw = sq_base >> 6;  // diagonal kv-block index for this wave

  bf16x8 qf[4];
  {
    const u16* qp = q + (size_t)sq_abs * (NHEADS * HD) + h * HD + l4 * 8;
#pragma unroll
    for (int kb = 0; kb < 4; ++kb) qf[kb] = *(const bf16x8*)(qp + kb * 32);
  }
  f32x4 po[8];
#pragma unroll
  for (int i = 0; i < 8; ++i) po[i] = f32x4{0.f, 0.f, 0.f, 0.f};
  float mrow = -1e30f;
  float lrow = 0.f;

  const int nb = 2 * qbb + 2;
  stage_kv512(k, vt, kvh, 0, Ks[0], Vs[0], t);
  __syncthreads();
  int cur = 0;

  for (int b = 0; b < nb; ++b) {
    if (b + 1 < nb) stage_kv512(k, vt, kvh, (b + 1) * 64, Ks[cur ^ 1], Vs[cur ^ 1], t);

    if (b <= bw) {  // wave-uniform causal skip of fully-masked tiles
      f32x4 st[4];
#pragma unroll
      for (int c = 0; c < 4; ++c) st[c] = f32x4{0.f, 0.f, 0.f, 0.f};
#pragma unroll
      for (int c = 0; c < 4; ++c) {
        const int row = c * 16 + l15;
#pragma unroll
        for (int kb = 0; kb < 4; ++kb) {
          const int slot = kb * 4 + l4;
          bf16x8 bk = *(const bf16x8*)((const char*)Ks[cur] + row * 256 + ((slot ^ (row & 7)) << 4));
          st[c] = __builtin_amdgcn_mfma_f32_16x16x32_bf16(bk, qf[kb], st[c], 0, 0, 0);
        }
      }

      if (b == bw) {  // diagonal block: causal mask
#pragma unroll
        for (int c = 0; c < 4; ++c)
#pragma unroll
          for (int r = 0; r < 4; ++r) {
            const int sk = b * 64 + c * 16 + l4 * 4 + r;
            if (sk > sq_abs) st[c][r] = -1e30f;
          }
      }

      float rmax = -3e38f;
#pragma unroll
      for (int c = 0; c < 4; ++c)
        rmax = fmaxf(rmax, fmaxf(fmaxf(st[c][0], st[c][1]), fmaxf(st[c][2], st[c][3])));
      rmax = fmaxf(rmax, __shfl_xor(rmax, 16, 64));
      rmax = fmaxf(rmax, __shfl_xor(rmax, 32, 64));

      const bool skip = __all(rmax <= mrow + 8.f);
      const float mnew = skip ? mrow : fmaxf(mrow, rmax);

      float rs = 0.f;
#pragma unroll
      for (int c = 0; c < 4; ++c) {
        const float e0 = exp2f(st[c][0] - mnew), e1 = exp2f(st[c][1] - mnew);
        const float e2 = exp2f(st[c][2] - mnew), e3 = exp2f(st[c][3] - mnew);
        st[c][0] = e0; st[c][1] = e1; st[c][2] = e2; st[c][3] = e3;
        rs += (e0 + e1) + (e2 + e3);
      }
      rs += __shfl_xor(rs, 16, 64);
      rs += __shfl_xor(rs, 32, 64);

      if (!skip) {
        const float alpha = exp2f(mrow - mnew);
        mrow = mnew;
        lrow = lrow * alpha + rs;
        float av[4];
#pragma unroll
        for (int r = 0; r < 4; ++r) av[r] = __shfl(alpha, l4 * 4 + r, 16);
#pragma unroll
        for (int db = 0; db < 8; ++db)
#pragma unroll
          for (int r = 0; r < 4; ++r) po[db][r] *= av[r];
      } else {
        lrow += rs;
      }

      u32 pk[4][2];
#pragma unroll
      for (int c = 0; c < 4; ++c) {
        pk[c][0] = (u32)f2bf(st[c][0]) | ((u32)f2bf(st[c][1]) << 16);
        pk[c][1] = (u32)f2bf(st[c][2]) | ((u32)f2bf(st[c][3]) << 16);
      }
      const int src01 = l15 + ((lane & 16) << 1);
      const int src23 = src01 + 16;
      const bool lo = (lane & 32) == 0;
#pragma unroll
      for (int kb2 = 0; kb2 < 2; ++kb2) {
        const int c0 = kb2 * 2, c1 = c0 + 1;
        const u32 a0 = (u32)__shfl((int)pk[c0][0], src01, 64);
        const u32 a1 = (u32)__shfl((int)pk[c0][1], src01, 64);
        const u32 a2 = (u32)__shfl((int)pk[c0][0], src23, 64);
        const u32 a3 = (u32)__shfl((int)pk[c0][1], src23, 64);
        const u32 b0 = (u32)__shfl((int)pk[c1][0], src01, 64);
        const u32 b1 = (u32)__shfl((int)pk[c1][1], src01, 64);
        const u32 b2 = (u32)__shfl((int)pk[c1][0], src23, 64);
        const u32 b3 = (u32)__shfl((int)pk[c1][1], src23, 64);
        u32x4 wq;
        wq.x = lo ? a0 : b0;
        wq.y = lo ? a1 : b1;
        wq.z = lo ? a2 : b2;
        wq.w = lo ? a3 : b3;
        const bf16x8 pa = __builtin_bit_cast(bf16x8, wq);
#pragma unroll
        for (int db = 0; db < 8; ++db) {
          const int vrow = db * 16 + l15;
          const int pslot = kb2 * 4 + l4;
          bf16x8 bv =
              *(const bf16x8*)((const char*)Vs[cur] + vrow * 128 + ((pslot ^ (vrow & 7)) << 4));
          po[db] = __builtin_amdgcn_mfma_f32_16x16x32_bf16(pa, bv, po[db], 0, 0, 0);
        }
      }
    }
    __syncthreads();
    cur ^= 1;
  }

  float rl[4];
#pragma unroll
  for (int r = 0; r < 4; ++r) rl[r] = 1.f / __shfl(lrow, l4 * 4 + r, 16);
#pragma unroll
  for (int db = 0; db < 8; ++db)
#pragma unroll
    for (int r = 0; r < 4; ++r) {
      const int sq = sq_base + l4 * 4 + r;
      const int d = db * 16 + l15;
      ctx[(size_t)sq * (NHEADS * HD) + h * HD + d] = f2bf(po[db][r] * rl[r]);
    }
}

extern "C" void kernel_launch(void* const* d_in, const int* in_sizes, int n_in,
                              void* d_out, int out_size, void* d_ws, size_t ws_size,
                              hipStream_t stream) {
  const float* hs = (const float*)d_in[0];
  const int* pos = (const int*)d_in[1];
  const float* Wq = (const float*)d_in[2];
  const float* Wk = (const float*)d_in[3];
  const float* Wv = (const float*)d_in[4];
  const float* Wo = (const float*)d_in[5];

  u16* ws = (u16*)d_ws;
  u16* Xb = ws;                                   // [2048][4096]
  u16* Wqt = Xb + (size_t)2048 * 4096;            // [4096][4096]
  u16* Wkt = Wqt + (size_t)4096 * 4096;           // [1024][4096]
  u16* Wvt = Wkt + (size_t)1024 * 4096;           // [1024][4096]
  u16* Wot = Wvt + (size_t)1024 * 4096;           // [4096][4096]
  u16* qb = Wot + (size_t)4096 * 4096;            // [2048][4096]
  u16* kb = qb + (size_t)2048 * 4096;             // [2048][1024]
  u16* vb = kb + (size_t)2048 * 1024;             // [2048][1024]
  u16* vtb = vb + (size_t)2048 * 1024;            // [1024][2048]
  u16* ctx = vtb + (size_t)1024 * 2048;           // [2048][4096]
  const size_t need = ((size_t)(ctx - ws) + (size_t)2048 * 4096) * 2;
  if (ws_size < need) return;

  // fused X conversion + Wq/Wk/Wv transposes
  prep_all<<<14336, 256, 0, stream>>>(hs, Xb, Wq, Wqt, Wk, Wkt, Wv, Wvt);

  // fused Q+K+V projections (192 gemm blocks, row-panel-per-XCD) + folded Wo transpose
  gemm8p32<<<256, 512, 0, stream>>>(Xb, Wqt, Wkt, Wvt, qb, kb, vb, Wo, Wot);

  // fused RoPE(q) + RoPE(k) + V transpose
  post_qkv<<<22528, 256, 0, stream>>>(qb, kb, vb, vtb, pos);

  // QBLK=128 kv-head-per-XCD attention
  attn_fwd<<<512, 512, 0, stream>>>(qb, kb, vtb, ctx);

  // output projection -> fp32 d_out
  gemm8p16<<<256, 512, 0, stream>>>(ctx, Wot, (float*)d_out);
}